// Round 1
// 461.254 us; speedup vs baseline: 1.0514x; 1.0514x over previous
//
#include <hip/hip_runtime.h>
#include <cstddef>

#define NRELS 8
#define EMB 128
#define HID 128
#define OUTD 256
#define HEADS 4
#define RANK 8
#define D2 512            // HEADS*HID, conv2 input dim
#define KCAT 192          // EMB + 64, concatenated K for residual+lora2 GEMM
#define NEG_SLOPE 0.2f
#define LN_EPS 1e-5f

typedef short bf16x8 __attribute__((ext_vector_type(8)));   // 8 bf16 in 4 VGPRs
typedef float f32x4 __attribute__((ext_vector_type(4)));

__device__ __forceinline__ unsigned short f2bf(float f) {   // RNE
  union { float f; unsigned u; } v; v.f = f;
  unsigned u = v.u;
  return (unsigned short)((u + 0x7fffu + ((u >> 16) & 1u)) >> 16);
}
__device__ __forceinline__ float bf2f(unsigned short u) {
  union { unsigned u; float f; } v; v.u = (unsigned)u << 16; return v.f;
}

// ---------------- Big-tile bf16 MFMA GEMM, bf16 output ----------------
__global__ __launch_bounds__(256) void gemm_big_h(const unsigned short* __restrict__ A,
    const unsigned short* __restrict__ B, unsigned short* __restrict__ C, int M, int N, int K) {
  __shared__ unsigned short As[128][36];
  __shared__ unsigned short Bs[128][36];
  const int tid = threadIdx.x;
  const int wave = tid >> 6;
  const int lane = tid & 63;
  const int wm = wave & 1;
  const int wn = wave >> 1;
  const int r16 = lane & 15;
  const int quad = lane >> 4;
  const int bm = blockIdx.x * 128;
  const int bn = blockIdx.y * 128;
  const int srow = tid >> 2;
  const int scol = (tid & 3) * 8;
  int ar0 = bm + srow;      if (ar0 >= M) ar0 = M - 1;
  int ar1 = bm + 64 + srow; if (ar1 >= M) ar1 = M - 1;
  const unsigned short* Ag0 = A + (size_t)ar0 * K + scol;
  const unsigned short* Ag1 = A + (size_t)ar1 * K + scol;
  const unsigned short* Bg0 = B + (size_t)(bn + srow) * K + scol;
  const unsigned short* Bg1 = B + (size_t)(bn + 64 + srow) * K + scol;
  f32x4 acc[4][4] = {};
  for (int k0 = 0; k0 < K; k0 += 32) {
    bf16x8 a0 = *(const bf16x8*)(Ag0 + k0);
    bf16x8 a1 = *(const bf16x8*)(Ag1 + k0);
    bf16x8 b0 = *(const bf16x8*)(Bg0 + k0);
    bf16x8 b1 = *(const bf16x8*)(Bg1 + k0);
    __syncthreads();
    *(bf16x8*)(&As[srow][scol]) = a0;
    *(bf16x8*)(&As[64 + srow][scol]) = a1;
    *(bf16x8*)(&Bs[srow][scol]) = b0;
    *(bf16x8*)(&Bs[64 + srow][scol]) = b1;
    __syncthreads();
    bf16x8 af[4], bfr[4];
#pragma unroll
    for (int mi = 0; mi < 4; ++mi)
      af[mi] = *(const bf16x8*)(&As[wm * 64 + mi * 16 + r16][quad * 8]);
#pragma unroll
    for (int ni = 0; ni < 4; ++ni)
      bfr[ni] = *(const bf16x8*)(&Bs[wn * 64 + ni * 16 + r16][quad * 8]);
#pragma unroll
    for (int mi = 0; mi < 4; ++mi)
#pragma unroll
      for (int ni = 0; ni < 4; ++ni)
        acc[mi][ni] = __builtin_amdgcn_mfma_f32_16x16x32_bf16(af[mi], bfr[ni], acc[mi][ni], 0, 0, 0);
  }
#pragma unroll
  for (int mi = 0; mi < 4; ++mi)
#pragma unroll
    for (int ni = 0; ni < 4; ++ni)
#pragma unroll
      for (int r = 0; r < 4; ++r) {
        int row = bm + wm * 64 + mi * 16 + quad * 4 + r;
        if (row < M)
          C[(size_t)row * N + bn + wn * 64 + ni * 16 + r16] = f2bf(acc[mi][ni][r]);
      }
}

// ---------------- Big-tile bf16 MFMA GEMM, fp32 output ----------------
__global__ __launch_bounds__(256) void gemm_big(const unsigned short* __restrict__ A,
    const unsigned short* __restrict__ B, float* __restrict__ C, int M, int N, int K) {
  __shared__ unsigned short As[128][36];
  __shared__ unsigned short Bs[128][36];
  const int tid = threadIdx.x;
  const int wave = tid >> 6;
  const int lane = tid & 63;
  const int wm = wave & 1;
  const int wn = wave >> 1;
  const int r16 = lane & 15;
  const int quad = lane >> 4;
  const int bm = blockIdx.x * 128;
  const int bn = blockIdx.y * 128;
  const int srow = tid >> 2;
  const int scol = (tid & 3) * 8;
  int ar0 = bm + srow;      if (ar0 >= M) ar0 = M - 1;
  int ar1 = bm + 64 + srow; if (ar1 >= M) ar1 = M - 1;
  const unsigned short* Ag0 = A + (size_t)ar0 * K + scol;
  const unsigned short* Ag1 = A + (size_t)ar1 * K + scol;
  const unsigned short* Bg0 = B + (size_t)(bn + srow) * K + scol;
  const unsigned short* Bg1 = B + (size_t)(bn + 64 + srow) * K + scol;
  f32x4 acc[4][4] = {};
  for (int k0 = 0; k0 < K; k0 += 32) {
    bf16x8 a0 = *(const bf16x8*)(Ag0 + k0);
    bf16x8 a1 = *(const bf16x8*)(Ag1 + k0);
    bf16x8 b0 = *(const bf16x8*)(Bg0 + k0);
    bf16x8 b1 = *(const bf16x8*)(Bg1 + k0);
    __syncthreads();
    *(bf16x8*)(&As[srow][scol]) = a0;
    *(bf16x8*)(&As[64 + srow][scol]) = a1;
    *(bf16x8*)(&Bs[srow][scol]) = b0;
    *(bf16x8*)(&Bs[64 + srow][scol]) = b1;
    __syncthreads();
    bf16x8 af[4], bfr[4];
#pragma unroll
    for (int mi = 0; mi < 4; ++mi)
      af[mi] = *(const bf16x8*)(&As[wm * 64 + mi * 16 + r16][quad * 8]);
#pragma unroll
    for (int ni = 0; ni < 4; ++ni)
      bfr[ni] = *(const bf16x8*)(&Bs[wn * 64 + ni * 16 + r16][quad * 8]);
#pragma unroll
    for (int mi = 0; mi < 4; ++mi)
#pragma unroll
      for (int ni = 0; ni < 4; ++ni)
        acc[mi][ni] = __builtin_amdgcn_mfma_f32_16x16x32_bf16(af[mi], bfr[ni], acc[mi][ni], 0, 0, 0);
  }
#pragma unroll
  for (int mi = 0; mi < 4; ++mi)
#pragma unroll
    for (int ni = 0; ni < 4; ++ni)
#pragma unroll
      for (int r = 0; r < 4; ++r) {
        int row = bm + wm * 64 + mi * 16 + quad * 4 + r;
        if (row < M)
          C[(size_t)row * N + bn + wn * 64 + ni * 16 + r16] = acc[mi][ni][r];
      }
}

// ---------------- 64x64 bf16 MFMA GEMM, fp32 out (N=64 P-projections) ----------------
__global__ __launch_bounds__(256) void gemm_bf16t(const unsigned short* __restrict__ A,
    const unsigned short* __restrict__ B, float* __restrict__ C, int M, int N, int K) {
  __shared__ unsigned short As[64][40];
  __shared__ unsigned short Bs[64][40];
  const int tid = threadIdx.x;
  const int wave = tid >> 6;
  const int lane = tid & 63;
  const int wm = wave & 1;
  const int wn = wave >> 1;
  const int r16 = lane & 15;
  const int quad = lane >> 4;
  const int bm = blockIdx.x * 64;
  const int bn = blockIdx.y * 64;
  const int srow = tid >> 2;
  const int schunk = tid & 3;
  int arow = bm + srow; if (arow >= M) arow = M - 1;
  const unsigned short* Ag = A + (size_t)arow * K + schunk * 8;
  const unsigned short* Bg = B + (size_t)(bn + srow) * K + schunk * 8;
  f32x4 acc[2][2] = {};
  for (int k0 = 0; k0 < K; k0 += 32) {
    bf16x8 av = *(const bf16x8*)(Ag + k0);
    bf16x8 bv = *(const bf16x8*)(Bg + k0);
    __syncthreads();
    *(bf16x8*)(&As[srow][schunk * 8]) = av;
    *(bf16x8*)(&Bs[srow][schunk * 8]) = bv;
    __syncthreads();
    bf16x8 af0 = *(const bf16x8*)(&As[wm * 32 + r16][quad * 8]);
    bf16x8 af1 = *(const bf16x8*)(&As[wm * 32 + 16 + r16][quad * 8]);
    bf16x8 bf0 = *(const bf16x8*)(&Bs[wn * 32 + r16][quad * 8]);
    bf16x8 bf1 = *(const bf16x8*)(&Bs[wn * 32 + 16 + r16][quad * 8]);
    acc[0][0] = __builtin_amdgcn_mfma_f32_16x16x32_bf16(af0, bf0, acc[0][0], 0, 0, 0);
    acc[0][1] = __builtin_amdgcn_mfma_f32_16x16x32_bf16(af0, bf1, acc[0][1], 0, 0, 0);
    acc[1][0] = __builtin_amdgcn_mfma_f32_16x16x32_bf16(af1, bf0, acc[1][0], 0, 0, 0);
    acc[1][1] = __builtin_amdgcn_mfma_f32_16x16x32_bf16(af1, bf1, acc[1][1], 0, 0, 0);
  }
#pragma unroll
  for (int mi = 0; mi < 2; ++mi)
#pragma unroll
    for (int ni = 0; ni < 2; ++ni)
#pragma unroll
      for (int r = 0; r < 4; ++r) {
        int row = bm + wm * 32 + mi * 16 + quad * 4 + r;
        if (row < M)
          C[(size_t)row * N + bn + wn * 32 + ni * 16 + r16] = acc[mi][ni][r];
      }
}

// ---------------- fp32 tiled GEMM (tiny M1/M2 precompute) ----------------
__global__ __launch_bounds__(256) void gemm_abt(const float* __restrict__ A,
    const float* __restrict__ B, float* __restrict__ C, int M, int N, int K) {
  __shared__ float As[32][64];
  __shared__ float Bs[32][64];
  const int tid = threadIdx.x;
  const int bm = blockIdx.y * 64;
  const int bn = blockIdx.x * 64;
  const int tx = tid & 15;
  const int ty = tid >> 4;
  const int lr = tid & 63;
  const int lq = tid >> 6;
  float acc[4][4] = {};
  for (int k0 = 0; k0 < K; k0 += 32) {
#pragma unroll
    for (int s = 0; s < 2; ++s) {
      const int q = lq + s * 4;
      const int gm = bm + lr;
      float4 va = make_float4(0.f, 0.f, 0.f, 0.f);
      if (gm < M) va = *(const float4*)(A + (size_t)gm * K + k0 + q * 4);
      As[q * 4 + 0][lr] = va.x; As[q * 4 + 1][lr] = va.y;
      As[q * 4 + 2][lr] = va.z; As[q * 4 + 3][lr] = va.w;
      const int gn = bn + lr;
      float4 vb = *(const float4*)(B + (size_t)gn * K + k0 + q * 4);
      Bs[q * 4 + 0][lr] = vb.x; Bs[q * 4 + 1][lr] = vb.y;
      Bs[q * 4 + 2][lr] = vb.z; Bs[q * 4 + 3][lr] = vb.w;
    }
    __syncthreads();
#pragma unroll
    for (int kk = 0; kk < 32; ++kk) {
      float a[4], b[4];
#pragma unroll
      for (int i2 = 0; i2 < 4; ++i2) { a[i2] = As[kk][ty * 4 + i2]; b[i2] = Bs[kk][tx * 4 + i2]; }
#pragma unroll
      for (int i2 = 0; i2 < 4; ++i2)
#pragma unroll
        for (int j2 = 0; j2 < 4; ++j2)
          acc[i2][j2] = fmaf(a[i2], b[j2], acc[i2][j2]);
    }
    __syncthreads();
  }
#pragma unroll
  for (int i2 = 0; i2 < 4; ++i2) {
    const int gm = bm + ty * 4 + i2;
    if (gm >= M) continue;
#pragma unroll
    for (int j2 = 0; j2 < 4; ++j2)
      C[(size_t)gm * N + bn + tx * 4 + j2] = acc[i2][j2];
  }
}

// ---------------- Fused prep: bf16 conversions + LoRA re-layouts + concat copies ----------------
__global__ void prep_all(const float* __restrict__ x0, const float* __restrict__ W1,
    const float* __restrict__ W2, const float* __restrict__ res_W,
    const float* __restrict__ A1, const float* __restrict__ A2,
    const float* __restrict__ B1, const float* __restrict__ B2,
    unsigned short* __restrict__ x0b, unsigned short* __restrict__ Acat,
    unsigned short* __restrict__ W1b, unsigned short* __restrict__ W2b,
    unsigned short* __restrict__ RWcat,
    float* __restrict__ Amat1, float* __restrict__ Amat2,
    unsigned short* __restrict__ Bmat1b, unsigned short* __restrict__ Bmat2b, int nx0) {
  int idx = blockIdx.x * 256 + threadIdx.x;
  if (idx < nx0) { unsigned short b = f2bf(x0[idx]); x0b[idx] = b;
    Acat[(size_t)(idx >> 7) * KCAT + (idx & 127)] = b; return; } idx -= nx0;
  if (idx < D2 * EMB) { W1b[idx] = f2bf(W1[idx]); return; } idx -= D2 * EMB;
  if (idx < OUTD * D2) { W2b[idx] = f2bf(W2[idx]); return; } idx -= OUTD * D2;
  if (idx < OUTD * EMB) { RWcat[(size_t)(idx >> 7) * KCAT + (idx & 127)] = f2bf(res_W[idx]); return; } idx -= OUTD * EMB;
  if (idx < 64 * EMB) { int d = idx % EMB, rk = idx / EMB, k = rk & 7, r = rk >> 3;
    Amat1[idx] = A1[(size_t)r * EMB * RANK + (size_t)d * RANK + k]; return; } idx -= 64 * EMB;
  if (idx < 64 * D2) { int d = idx % D2, rk = idx / D2, k = rk & 7, r = rk >> 3;
    Amat2[idx] = A2[(size_t)r * D2 * RANK + (size_t)d * RANK + k]; return; } idx -= 64 * D2;
  if (idx < 64 * EMB) { int d = idx % EMB, rk = idx / EMB, k = rk & 7, r = rk >> 3;
    Bmat1b[idx] = f2bf(B1[(size_t)r * EMB * RANK + (size_t)d * RANK + k]); return; } idx -= 64 * EMB;
  if (idx < 64 * D2) { int d = idx % D2, rk = idx / D2, k = rk & 7, r = rk >> 3;
    Bmat2b[idx] = f2bf(B2[(size_t)r * D2 * RANK + (size_t)d * RANK + k]); }
}

// ---------------- Matt folds ----------------
__global__ void fold_att(const float* __restrict__ M1, const float* __restrict__ attR1,
                         const float* __restrict__ M2, const float* __restrict__ attR2,
                         float* __restrict__ Matt1, float* __restrict__ Matt2) {
  int t = threadIdx.x;
  if (blockIdx.x == 0) {
    int h = t & 3, rk = t >> 2;
    float s = 0.f;
    for (int c = 0; c < HID; ++c)
      s = fmaf(M1[(size_t)rk * D2 + h * HID + c], attR1[h * HID + c], s);
    Matt1[rk * 4 + h] = s;
  } else if (t < 64) {
    float s = 0.f;
    for (int c = 0; c < OUTD; ++c) s = fmaf(M2[(size_t)t * OUTD + c], attR2[c], s);
    Matt2[t] = s;
  }
}

// ---------------- Build GEMM-B operands for the LoRA factorization ----------------
// M1T [512][256] bf16 block-diag: M1T[c][h*64+rk] = (c>>7==h) ? M1[rk][c] : 0
// RWcat cols 128..191: RWcat[c][128+rk] = M2[rk][c]
__global__ void build_MT(const float* __restrict__ M1, const float* __restrict__ M2,
                         unsigned short* __restrict__ M1T, unsigned short* __restrict__ RWcat) {
  int idx = blockIdx.x * 256 + threadIdx.x;
  if (idx < 512 * 256) {
    int c = idx >> 8, s = idx & 255;
    int h = s >> 6, rk = s & 63;
    float v = ((c >> 7) == h) ? M1[(size_t)rk * D2 + c] : 0.f;
    M1T[idx] = f2bf(v);
  } else {
    idx -= 512 * 256;
    if (idx < 256 * 64) {
      int c = idx >> 6, rk = idx & 63;
      RWcat[(size_t)c * KCAT + 128 + rk] = f2bf(M2[(size_t)rk * OUTD + c]);
    }
  }
}

// ---------------- Coalesced rowdots (wave per row, shuffle reduce) ----------------
__global__ __launch_bounds__(256) void rowdot1_fast(const unsigned short* __restrict__ Z,
    const float* __restrict__ attL, const float* __restrict__ attR,
    float* __restrict__ al, float* __restrict__ ar, int Nn) {
  int wi = blockIdx.x * 4 + (threadIdx.x >> 6);
  int lane = threadIdx.x & 63;
  if (wi >= Nn * 4) return;
  int n = wi >> 2, h = wi & 3;
  const ushort2* z = (const ushort2*)(Z + (size_t)n * D2 + h * HID);
  ushort2 zv = z[lane];
  float2 L = ((const float2*)(attL + h * HID))[lane];
  float2 R = ((const float2*)(attR + h * HID))[lane];
  float z0 = bf2f(zv.x), z1 = bf2f(zv.y);
  float sl = z0 * L.x + z1 * L.y;
  float sr = z0 * R.x + z1 * R.y;
  for (int o = 32; o > 0; o >>= 1) { sl += __shfl_down(sl, o, 64); sr += __shfl_down(sr, o, 64); }
  if (lane == 0) { al[wi] = sl; ar[wi] = sr; }
}

__global__ __launch_bounds__(256) void rowdot2_fast(const unsigned short* __restrict__ Z,
    const float* __restrict__ attL, const float* __restrict__ attR,
    float* __restrict__ al, float* __restrict__ ar, int Nn) {
  int n = blockIdx.x * 4 + (threadIdx.x >> 6);
  int lane = threadIdx.x & 63;
  if (n >= Nn) return;
  const uint2* z = (const uint2*)(Z + (size_t)n * OUTD);
  uint2 zv = z[lane];
  float4 L = ((const float4*)attL)[lane];
  float4 R = ((const float4*)attR)[lane];
  float z0 = bf2f((unsigned short)(zv.x & 0xffff)), z1 = bf2f((unsigned short)(zv.x >> 16));
  float z2 = bf2f((unsigned short)(zv.y & 0xffff)), z3 = bf2f((unsigned short)(zv.y >> 16));
  float sl = z0 * L.x + z1 * L.y + z2 * L.z + z3 * L.w;
  float sr = z0 * R.x + z1 * R.y + z2 * R.z + z3 * R.w;
  for (int o = 32; o > 0; o >>= 1) { sl += __shfl_down(sl, o, 64); sr += __shfl_down(sr, o, 64); }
  if (lane == 0) { al[n] = sl; ar[n] = sr; }
}

// ---------------- CSR build ----------------
__global__ void hist_kernel(const int* __restrict__ ii, int* __restrict__ deg, int E) {
  int e = blockIdx.x * blockDim.x + threadIdx.x;
  if (e < E) atomicAdd(&deg[ii[e]], 1);
}

__global__ __launch_bounds__(1024) void exscan_kernel(const int* __restrict__ deg,
                                                      int* __restrict__ rowstart, int n) {
  __shared__ int wsum[16];
  int t = threadIdx.x;
  int lane = t & 63, wid = t >> 6;
  int carry = 0;
  for (int base = 0; base < n; base += 1024) {
    int v = (base + t < n) ? deg[base + t] : 0;
    int x = v;
#pragma unroll
    for (int o = 1; o < 64; o <<= 1) {
      int y = __shfl_up(x, o, 64);
      if (lane >= o) x += y;
    }
    if (lane == 63) wsum[wid] = x;
    __syncthreads();
    if (t == 0) {
      int s = carry;
      for (int w2 = 0; w2 < 16; ++w2) { int tmp = wsum[w2]; wsum[w2] = s; s += tmp; }
      carry = s;
    }
    __syncthreads();
    int incl = x + wsum[wid];
    if (base + t < n) rowstart[base + t] = incl - v;
    __syncthreads();
  }
  if (t == 0) rowstart[n] = carry;
}

__global__ void scatter_kernel(const int* __restrict__ ii, const int* __restrict__ rowstart,
                               int* __restrict__ cursor, int* __restrict__ slot_of, int E) {
  int e = blockIdx.x * blockDim.x + threadIdx.x;
  if (e >= E) return;
  int i = ii[e];
  int p = atomicAdd(&cursor[i], 1);
  slot_of[e] = rowstart[i] + p;
}

// ---------------- Layer-1 edge logits -> packed records at CSR slots ----------------
// rec1 (16 floats): [j, rt, ex0, ex1 | ex2, ex3, low0, low1 | low2..low5 | low6, low7, 0, 0]
__global__ void edge_alpha1(const int* __restrict__ ji, const int* __restrict__ ii,
                            const int* __restrict__ et, const int* __restrict__ slot_of,
                            const float* __restrict__ P1,
                            const float* __restrict__ al1, const float* __restrict__ ar1,
                            const float* __restrict__ relb1, const float* __restrict__ Matt1,
                            float4* __restrict__ recs1, int E) {
  int e = blockIdx.x * blockDim.x + threadIdx.x;
  if (e >= E) return;
  int j = ji[e], i = ii[e], rt = et[e];
  float low[RANK];
#pragma unroll
  for (int k = 0; k < RANK; ++k) low[k] = P1[(size_t)j * 64 + rt * RANK + k];
  float exv[HEADS];
#pragma unroll
  for (int h = 0; h < HEADS; ++h) {
    float a = al1[i * 4 + h] + ar1[j * 4 + h] + relb1[rt * 4 + h];
#pragma unroll
    for (int k = 0; k < RANK; ++k) a = fmaf(low[k], Matt1[(rt * RANK + k) * 4 + h], a);
    a = (a > 0.f) ? a : NEG_SLOPE * a;
    exv[h] = expf(a);
  }
  float4* rp = recs1 + (size_t)slot_of[e] * 4;
  rp[0] = make_float4(__int_as_float(j), __int_as_float(rt), exv[0], exv[1]);
  rp[1] = make_float4(exv[2], exv[3], low[0], low[1]);
  rp[2] = make_float4(low[2], low[3], low[4], low[5]);
  rp[3] = make_float4(low[6], low[7], 0.f, 0.f);
}

// ---------------- Layer-1 Q/den: wave per node, lane = (rt*8+k) slot ----------------
// Q1[i][h*64 + rt*8+k] = rden1[i][h][rt] * sum_{e into i, rel rt} ex_eh * low_ek
__global__ __launch_bounds__(256) void qden1(const float4* __restrict__ recs1,
    const int* __restrict__ rowstart, unsigned short* __restrict__ Q1b,
    float* __restrict__ rden1, int Nn) {
  const int wid = threadIdx.x >> 6, lane = threadIdx.x & 63;
  const int i = blockIdx.x * 4 + wid;
  if (i >= Nn) return;
  const int rt_mine = lane >> 3, k = lane & 7;
  const int s0 = rowstart[i], deg = rowstart[i + 1] - s0;
  const float* rf = (const float*)recs1;
  float q0 = 0.f, q1 = 0.f, q2 = 0.f, q3 = 0.f;
  float d0 = 0.f, d1 = 0.f, d2 = 0.f, d3 = 0.f;
  for (int p = 0; p < deg; ++p) {
    size_t base = (size_t)(s0 + p) * 16;
    int rt = __float_as_int(rf[base + 1]);
    float2 e01 = *(const float2*)(rf + base + 2);
    float2 e23 = *(const float2*)(rf + base + 4);
    float lowk = rf[base + 6 + k];
    if (rt == rt_mine) {
      q0 = fmaf(e01.x, lowk, q0); q1 = fmaf(e01.y, lowk, q1);
      q2 = fmaf(e23.x, lowk, q2); q3 = fmaf(e23.y, lowk, q3);
      d0 += e01.x; d1 += e01.y; d2 += e23.x; d3 += e23.y;
    }
  }
  float r0 = (d0 > 0.f) ? 1.f / d0 : 0.f;
  float r1 = (d1 > 0.f) ? 1.f / d1 : 0.f;
  float r2 = (d2 > 0.f) ? 1.f / d2 : 0.f;
  float r3 = (d3 > 0.f) ? 1.f / d3 : 0.f;
  size_t qb = (size_t)i * 256;
  Q1b[qb + 0 * 64 + lane] = f2bf(q0 * r0);
  Q1b[qb + 1 * 64 + lane] = f2bf(q1 * r1);
  Q1b[qb + 2 * 64 + lane] = f2bf(q2 * r2);
  Q1b[qb + 3 * 64 + lane] = f2bf(q3 * r3);
  if (k == 0) {
    size_t db = (size_t)i * 32;
    rden1[db + 0 * 8 + rt_mine] = r0;
    rden1[db + 1 * 8 + rt_mine] = r1;
    rden1[db + 2 * 8 + rt_mine] = r2;
    rden1[db + 3 * 8 + rt_mine] = r3;
  }
}

// ---------------- Layer-1 gather (lite): pure w*z_j accumulation + lora add + elu ----------------
__global__ __launch_bounds__(256) void node_agg1_lite(const float4* __restrict__ recs1,
    const int* __restrict__ rowstart, const unsigned short* __restrict__ z1b,
    const unsigned short* __restrict__ L1b, const float* __restrict__ rden1,
    const float* __restrict__ bias1, unsigned short* __restrict__ h1out, int Nn) {
  const int wv = threadIdx.x >> 6;      // wave == head
  const int lane = threadIdx.x & 63;
  const int i = blockIdx.x;
  __shared__ float denS[4][NRELS];
  if (lane < NRELS) denS[wv][lane] = rden1[(size_t)i * 32 + wv * 8 + lane];
  // wave-synchronous LDS (each wave writes+reads its own row), no barrier
  const int s0 = rowstart[i];
  const int deg = rowstart[i + 1] - s0;
  const int c0 = wv * 128 + lane * 2;
  unsigned lv = *(const unsigned*)(L1b + (size_t)i * D2 + c0);  // lora contribution
  float2 bv = *(const float2*)(bias1 + c0);
  float acc0 = 0.f, acc1 = 0.f;
  float4 r0, r1;
  unsigned zc = 0;
  if (deg > 0) {
    const float4* rp = recs1 + (size_t)s0 * 4;
    r0 = rp[0]; r1 = rp[1];
    zc = *(const unsigned*)(z1b + (size_t)__float_as_int(r0.x) * D2 + c0);
  }
  for (int p = 0; p < deg; ++p) {
    float4 n0, n1;
    const bool more = (p + 1 < deg);
    if (more) {
      const float4* rp = recs1 + (size_t)(s0 + p + 1) * 4;
      n0 = rp[0]; n1 = rp[1];
    }
    int rt = __float_as_int(r0.y);
    float exh = (wv & 2) ? ((wv & 1) ? r1.y : r1.x) : ((wv & 1) ? r0.w : r0.z);
    float w = exh * denS[wv][rt];
    acc0 = fmaf(w, bf2f((unsigned short)(zc & 0xffff)), acc0);
    acc1 = fmaf(w, bf2f((unsigned short)(zc >> 16)), acc1);
    if (more) {
      r0 = n0; r1 = n1;
      zc = *(const unsigned*)(z1b + (size_t)__float_as_int(n0.x) * D2 + c0);
    }
  }
  float e0 = acc0 + bf2f((unsigned short)(lv & 0xffff)) + bv.x;
  float e1 = acc1 + bf2f((unsigned short)(lv >> 16)) + bv.y;
  e0 = e0 > 0.f ? e0 : expm1f(e0);
  e1 = e1 > 0.f ? e1 : expm1f(e1);
  unsigned ov = (unsigned)f2bf(e0) | ((unsigned)f2bf(e1) << 16);
  *(unsigned*)(h1out + (size_t)i * D2 + c0) = ov;
}

// ---------------- Layer-2 edge logits -> packed records ----------------
// rec2 (12 floats): [j, rt, ex, low0 | low1..low4 | low5, low6, low7, 0]
__global__ void edge_alpha2(const int* __restrict__ ji, const int* __restrict__ ii,
                            const int* __restrict__ et, const int* __restrict__ slot_of,
                            const float* __restrict__ P2,
                            const float* __restrict__ al2, const float* __restrict__ ar2,
                            const float* __restrict__ relb2, const float* __restrict__ Matt2,
                            float4* __restrict__ recs2, int E) {
  int e = blockIdx.x * blockDim.x + threadIdx.x;
  if (e >= E) return;
  int j = ji[e], i = ii[e], rt = et[e];
  float low[RANK];
#pragma unroll
  for (int k = 0; k < RANK; ++k) low[k] = P2[(size_t)j * 64 + rt * RANK + k];
  float a = al2[i] + ar2[j] + relb2[rt];
#pragma unroll
  for (int k = 0; k < RANK; ++k) a = fmaf(low[k], Matt2[rt * RANK + k], a);
  a = (a > 0.f) ? a : NEG_SLOPE * a;
  float ex = expf(a);
  float4* rp = recs2 + (size_t)slot_of[e] * 3;
  rp[0] = make_float4(__int_as_float(j), __int_as_float(rt), ex, low[0]);
  rp[1] = make_float4(low[1], low[2], low[3], low[4]);
  rp[2] = make_float4(low[5], low[6], low[7], 0.f);
}

// ---------------- Layer-2 Q/den: wave per node; writes Q into Acat cols 128..191 ----------------
__global__ __launch_bounds__(256) void qden2(const float4* __restrict__ recs2,
    const int* __restrict__ rowstart, unsigned short* __restrict__ Acat,
    float* __restrict__ rden2, int Nn) {
  const int wid = threadIdx.x >> 6, lane = threadIdx.x & 63;
  const int i = blockIdx.x * 4 + wid;
  if (i >= Nn) return;
  const int rt_mine = lane >> 3, k = lane & 7;
  const int s0 = rowstart[i], deg = rowstart[i + 1] - s0;
  const float* rf = (const float*)recs2;
  float q = 0.f, d = 0.f;
  for (int p = 0; p < deg; ++p) {
    size_t base = (size_t)(s0 + p) * 12;
    int rt = __float_as_int(rf[base + 1]);
    float ex = rf[base + 2];
    float lowk = rf[base + 3 + k];
    if (rt == rt_mine) { q = fmaf(ex, lowk, q); d += ex; }
  }
  float rd = (d > 0.f) ? 1.f / d : 0.f;
  Acat[(size_t)i * KCAT + 128 + lane] = f2bf(q * rd);
  if (k == 0) rden2[(size_t)i * 8 + rt_mine] = rd;
}

// ---------------- Layer-2 gather (lite) + residual+lora (o2) + bias + LN -> out ----------------
__global__ __launch_bounds__(256) void node_agg2_lite(const float4* __restrict__ recs2,
    const int* __restrict__ rowstart, const unsigned short* __restrict__ z2b,
    const float* __restrict__ rden2, const float* __restrict__ o2,
    const float* __restrict__ bias2, const float* __restrict__ res_b,
    const float* __restrict__ ln_g, const float* __restrict__ ln_b,
    float* __restrict__ y, int Nn) {
  const int wid = threadIdx.x >> 6;
  const int lane = threadIdx.x & 63;
  const int i = blockIdx.x * 4 + wid;
  if (i >= Nn) return;
  __shared__ float denS[4][NRELS];
  if (lane < NRELS) denS[wid][lane] = rden2[(size_t)i * 8 + lane];
  // wave-synchronous LDS, no barrier
  const int s0 = rowstart[i];
  const int deg = rowstart[i + 1] - s0;
  const int c0 = lane * 4;
  float acc[4] = {};
  float4 r0;
  uint2 zc = make_uint2(0u, 0u);
  if (deg > 0) {
    r0 = recs2[(size_t)s0 * 3];
    zc = *(const uint2*)(z2b + (size_t)__float_as_int(r0.x) * OUTD + c0);
  }
  for (int p = 0; p < deg; ++p) {
    float4 n0;
    const bool more = (p + 1 < deg);
    if (more) n0 = recs2[(size_t)(s0 + p + 1) * 3];
    int rt = __float_as_int(r0.y);
    float w = r0.z * denS[wid][rt];
    acc[0] = fmaf(w, bf2f((unsigned short)(zc.x & 0xffff)), acc[0]);
    acc[1] = fmaf(w, bf2f((unsigned short)(zc.x >> 16)), acc[1]);
    acc[2] = fmaf(w, bf2f((unsigned short)(zc.y & 0xffff)), acc[2]);
    acc[3] = fmaf(w, bf2f((unsigned short)(zc.y >> 16)), acc[3]);
    if (more) {
      r0 = n0;
      zc = *(const uint2*)(z2b + (size_t)__float_as_int(n0.x) * OUTD + c0);
    }
  }
  float4 rsv = *(const float4*)(o2 + (size_t)i * OUTD + c0);   // residual + lora2
  float4 b2 = *(const float4*)(bias2 + c0);
  float4 rb = *(const float4*)(res_b + c0);
  float vv[4];
  vv[0] = acc[0] + rsv.x + b2.x + rb.x;
  vv[1] = acc[1] + rsv.y + b2.y + rb.y;
  vv[2] = acc[2] + rsv.z + b2.z + rb.z;
  vv[3] = acc[3] + rsv.w + b2.w + rb.w;
  float s = vv[0] + vv[1] + vv[2] + vv[3];
  for (int o = 32; o > 0; o >>= 1) s += __shfl_xor(s, o, 64);
  float mu = s * (1.f / OUTD);
  float q = 0.f;
#pragma unroll
  for (int k = 0; k < 4; ++k) { float d = vv[k] - mu; q += d * d; }
  for (int o = 32; o > 0; o >>= 1) q += __shfl_xor(q, o, 64);
  float rstd = rsqrtf(q * (1.f / OUTD) + LN_EPS);
  float4 g = *(const float4*)(ln_g + c0);
  float4 bb = *(const float4*)(ln_b + c0);
  float4 ov;
  ov.x = (vv[0] - mu) * rstd * g.x + bb.x;
  ov.y = (vv[1] - mu) * rstd * g.y + bb.y;
  ov.z = (vv[2] - mu) * rstd * g.z + bb.z;
  ov.w = (vv[3] - mu) * rstd * g.w + bb.w;
  *(float4*)(y + (size_t)i * OUTD + c0) = ov;
}

extern "C" void kernel_launch(void* const* d_in, const int* in_sizes, int n_in,
                              void* d_out, int out_size, void* d_ws, size_t ws_size,
                              hipStream_t stream) {
  const float* x0     = (const float*)d_in[0];
  const float* A1     = (const float*)d_in[1];
  const float* B1     = (const float*)d_in[2];
  const float* W1     = (const float*)d_in[3];
  const float* attL1  = (const float*)d_in[4];
  const float* attR1  = (const float*)d_in[5];
  const float* relb1  = (const float*)d_in[6];
  const float* bias1  = (const float*)d_in[7];
  const float* A2     = (const float*)d_in[8];
  const float* B2     = (const float*)d_in[9];
  const float* W2     = (const float*)d_in[10];
  const float* attL2  = (const float*)d_in[11];
  const float* attR2  = (const float*)d_in[12];
  const float* relb2  = (const float*)d_in[13];
  const float* bias2  = (const float*)d_in[14];
  const float* res_W  = (const float*)d_in[15];
  const float* res_b  = (const float*)d_in[16];
  const float* ln_g   = (const float*)d_in[17];
  const float* ln_b   = (const float*)d_in[18];
  const int*   eidx   = (const int*)d_in[19];
  const int*   etype  = (const int*)d_in[20];
  float* out = (float*)d_out;

  const int Nn = in_sizes[0] / EMB;     // 30000
  const int E  = in_sizes[20];          // 150000
  const int* ji = eidx;
  const int* ii = eidx + E;

  // ---- workspace carve-up (float units; 16B alignment preserved) ----
  float* w = (float*)d_ws;
  size_t off = 0;
  float* o2    = w + off; off += (size_t)Nn * OUTD;   // ALSO aliased as L1b (bf16 [Nn][512])
  float* P1    = w + off; off += (size_t)Nn * 64;     // ALSO aliased (with P2) as Q1b (bf16 [Nn][256])
  float* P2    = w + off; off += (size_t)Nn * 64;
  float* M1    = w + off; off += 64 * D2;
  float* M2    = w + off; off += 64 * OUTD;
  float* Amat1 = w + off; off += 64 * EMB;
  float* Amat2 = w + off; off += 64 * D2;
  float* Matt1 = w + off; off += 64 * 4;
  float* Matt2 = w + off; off += 64;
  float* al1   = w + off; off += (size_t)Nn * 4;
  float* ar1   = w + off; off += (size_t)Nn * 4;
  float* al2   = w + off; off += (size_t)Nn;
  float* ar2   = w + off; off += (size_t)Nn;
  float4* recs1 = (float4*)(w + off); off += (size_t)E * 16;
  float4* recs2 = (float4*)(w + off); off += (size_t)E * 12;
  unsigned short* z1b    = (unsigned short*)(w + off); off += (size_t)Nn * D2 / 2;
  unsigned short* z2b    = (unsigned short*)(w + off); off += (size_t)Nn * OUTD / 2;
  unsigned short* x0b    = (unsigned short*)(w + off); off += (size_t)Nn * EMB / 2;
  unsigned short* h1b    = (unsigned short*)(w + off); off += (size_t)Nn * D2 / 2;
  unsigned short* W1b    = (unsigned short*)(w + off); off += (size_t)D2 * EMB / 2;
  unsigned short* W2b    = (unsigned short*)(w + off); off += (size_t)OUTD * D2 / 2;
  unsigned short* Bmat1b = (unsigned short*)(w + off); off += (size_t)64 * EMB / 2;
  unsigned short* Bmat2b = (unsigned short*)(w + off); off += (size_t)64 * D2 / 2;
  unsigned short* Acat   = (unsigned short*)(w + off); off += (size_t)Nn * KCAT / 2;
  unsigned short* RWcat  = (unsigned short*)(w + off); off += (size_t)OUTD * KCAT / 2;
  unsigned short* M1T    = (unsigned short*)(w + off); off += (size_t)512 * 256 / 2;
  float* rden1  = w + off; off += (size_t)Nn * 32;
  float* rden2  = w + off; off += (size_t)Nn * 8;
  int* ideg     = (int*)(w + off); off += (size_t)Nn;
  int* cursor   = (int*)(w + off); off += (size_t)Nn;
  int* slot_of  = (int*)(w + off); off += (size_t)E;
  int* rowstart = (int*)(w + off); off += (size_t)Nn + 1;
  (void)ws_size; (void)n_in; (void)out_size;

  // Aliases (lifetimes verified):
  //  Q1b over P1+P2: P1 dead after edge_alpha1; P2 written later (layer 2) after Q1b is dead.
  //  L1b over o2:    o2 written in layer 2 (after node_agg1_lite consumed L1b).
  unsigned short* Q1b = (unsigned short*)P1;   // [Nn][256] bf16
  unsigned short* L1b = (unsigned short*)o2;   // [Nn][512] bf16

  const int MT64 = (Nn + 63) / 64;
  const int MT128 = (Nn + 127) / 128;
  const int NB4 = (Nn + 3) / 4;

  // 0) CSR build
  (void)hipMemsetAsync(ideg, 0, (size_t)Nn * sizeof(int), stream);
  (void)hipMemsetAsync(cursor, 0, (size_t)Nn * sizeof(int), stream);
  hist_kernel<<<(E + 255) / 256, 256, 0, stream>>>(ii, ideg, E);
  exscan_kernel<<<1, 1024, 0, stream>>>(ideg, rowstart, Nn);
  scatter_kernel<<<(E + 255) / 256, 256, 0, stream>>>(ii, rowstart, cursor, slot_of, E);

  // 1) fused conversions + LoRA re-layouts + concat copies
  {
    int nx0 = Nn * EMB;
    int total = nx0 + D2 * EMB + OUTD * D2 + OUTD * EMB + 64 * EMB + 64 * D2 + 64 * EMB + 64 * D2;
    prep_all<<<(total + 255) / 256, 256, 0, stream>>>(x0, W1, W2, res_W, A1, A2, B1, B2,
        x0b, Acat, W1b, W2b, RWcat, Amat1, Amat2, Bmat1b, Bmat2b, nx0);
  }

  // 2) M1/M2 + Matt folds + GEMM-B operand builds
  gemm_abt<<<dim3(D2 / 64, 1), 256, 0, stream>>>(Amat1, W1, M1, 64, D2, EMB);
  gemm_abt<<<dim3(OUTD / 64, 1), 256, 0, stream>>>(Amat2, W2, M2, 64, OUTD, D2);
  fold_att<<<2, 256, 0, stream>>>(M1, attR1, M2, attR2, Matt1, Matt2);
  build_MT<<<(512 * 256 + 256 * 64 + 255) / 256, 256, 0, stream>>>(M1, M2, M1T, RWcat);

  // 3) Layer-1 node GEMMs
  gemm_big_h<<<dim3(MT128, D2 / 128), 256, 0, stream>>>(x0b, W1b, z1b, Nn, D2, EMB);
  gemm_bf16t<<<dim3(MT64, 1), 256, 0, stream>>>(x0b, Bmat1b, P1, Nn, 64, EMB);

  // 4) attention dots
  rowdot1_fast<<<Nn, 256, 0, stream>>>(z1b, attL1, attR1, al1, ar1, Nn);

  // 5) Layer-1 edge logits; per-node Q/den; LoRA GEMM; lite gather
  edge_alpha1<<<(E + 255) / 256, 256, 0, stream>>>(ji, ii, etype, slot_of, P1, al1, ar1,
                                                   relb1, Matt1, recs1, E);
  qden1<<<NB4, 256, 0, stream>>>(recs1, rowstart, Q1b, rden1, Nn);
  gemm_big_h<<<dim3(MT128, D2 / 128), 256, 0, stream>>>(Q1b, M1T, L1b, Nn, D2, 256);
  node_agg1_lite<<<Nn, 256, 0, stream>>>(recs1, rowstart, z1b, L1b, rden1, bias1, h1b, Nn);

  // 6) Layer-2 node GEMMs
  gemm_big_h<<<dim3(MT128, OUTD / 128), 256, 0, stream>>>(h1b, W2b, z2b, Nn, OUTD, D2);
  gemm_bf16t<<<dim3(MT64, 1), 256, 0, stream>>>(h1b, Bmat2b, P2, Nn, 64, D2);

  // 7) Layer-2 attention dots
  rowdot2_fast<<<NB4, 256, 0, stream>>>(z2b, attL2, attR2, al2, ar2, Nn);

  // 8) Layer-2 edge logits; Q/den (fills Acat cols 128..191); fused residual+lora GEMM; lite gather+LN
  edge_alpha2<<<(E + 255) / 256, 256, 0, stream>>>(ji, ii, etype, slot_of, P2, al2, ar2,
                                                   relb2, Matt2, recs2, E);
  qden2<<<NB4, 256, 0, stream>>>(recs2, rowstart, Acat, rden2, Nn);
  gemm_big<<<dim3(MT128, OUTD / 128), 256, 0, stream>>>(Acat, RWcat, o2, Nn, OUTD, KCAT);
  node_agg2_lite<<<NB4, 256, 0, stream>>>(recs2, rowstart, z2b, rden2, o2, bias2, res_b,
                                          ln_g, ln_b, out, Nn);
}

// Round 2
// 415.777 us; speedup vs baseline: 1.1664x; 1.1094x over previous
//
#include <hip/hip_runtime.h>
#include <cstddef>

#define NRELS 8
#define EMB 128
#define HID 128
#define OUTD 256
#define HEADS 4
#define RANK 8
#define D2 512            // HEADS*HID, conv2 input dim
#define KCAT 192          // EMB + 64, concatenated K for residual+lora2 GEMM
#define NEG_SLOPE 0.2f
#define LN_EPS 1e-5f

typedef short bf16x8 __attribute__((ext_vector_type(8)));   // 8 bf16 in 4 VGPRs
typedef float f32x4 __attribute__((ext_vector_type(4)));

__device__ __forceinline__ unsigned short f2bf(float f) {   // RNE
  union { float f; unsigned u; } v; v.f = f;
  unsigned u = v.u;
  return (unsigned short)((u + 0x7fffu + ((u >> 16) & 1u)) >> 16);
}
__device__ __forceinline__ float bf2f(unsigned short u) {
  union { unsigned u; float f; } v; v.u = (unsigned)u << 16; return v.f;
}

// ---------------- Big-tile bf16 MFMA GEMM, bf16 output ----------------
// ATT: 0 none; 1 fused att-dots per-head (N=512, head=blockIdx.y, direct store);
//      2 fused att-dots single-head (N=256, atomicAdd over col-blocks).
// BIAS: add bias[col] before bf16 rounding.
template<int ATT, int BIAS>
__global__ __launch_bounds__(256) void gemm_big_h(const unsigned short* __restrict__ A,
    const unsigned short* __restrict__ B, unsigned short* __restrict__ C, int M, int N, int K,
    const float* __restrict__ bias, const float* __restrict__ attL,
    const float* __restrict__ attR, float* __restrict__ al, float* __restrict__ ar) {
  __shared__ unsigned short As[128][36];
  __shared__ unsigned short Bs[128][36];
  __shared__ float pL[2][128];
  __shared__ float pR[2][128];
  const int tid = threadIdx.x;
  const int wave = tid >> 6;
  const int lane = tid & 63;
  const int wm = wave & 1;
  const int wn = wave >> 1;
  const int r16 = lane & 15;
  const int quad = lane >> 4;
  const int bm = blockIdx.x * 128;
  const int bn = blockIdx.y * 128;
  const int srow = tid >> 2;
  const int scol = (tid & 3) * 8;
  int ar0 = bm + srow;      if (ar0 >= M) ar0 = M - 1;
  int ar1 = bm + 64 + srow; if (ar1 >= M) ar1 = M - 1;
  const unsigned short* Ag0 = A + (size_t)ar0 * K + scol;
  const unsigned short* Ag1 = A + (size_t)ar1 * K + scol;
  const unsigned short* Bg0 = B + (size_t)(bn + srow) * K + scol;
  const unsigned short* Bg1 = B + (size_t)(bn + 64 + srow) * K + scol;
  f32x4 acc[4][4] = {};
  for (int k0 = 0; k0 < K; k0 += 32) {
    bf16x8 a0 = *(const bf16x8*)(Ag0 + k0);
    bf16x8 a1 = *(const bf16x8*)(Ag1 + k0);
    bf16x8 b0 = *(const bf16x8*)(Bg0 + k0);
    bf16x8 b1 = *(const bf16x8*)(Bg1 + k0);
    __syncthreads();
    *(bf16x8*)(&As[srow][scol]) = a0;
    *(bf16x8*)(&As[64 + srow][scol]) = a1;
    *(bf16x8*)(&Bs[srow][scol]) = b0;
    *(bf16x8*)(&Bs[64 + srow][scol]) = b1;
    __syncthreads();
    bf16x8 af[4], bfr[4];
#pragma unroll
    for (int mi = 0; mi < 4; ++mi)
      af[mi] = *(const bf16x8*)(&As[wm * 64 + mi * 16 + r16][quad * 8]);
#pragma unroll
    for (int ni = 0; ni < 4; ++ni)
      bfr[ni] = *(const bf16x8*)(&Bs[wn * 64 + ni * 16 + r16][quad * 8]);
#pragma unroll
    for (int mi = 0; mi < 4; ++mi)
#pragma unroll
      for (int ni = 0; ni < 4; ++ni)
        acc[mi][ni] = __builtin_amdgcn_mfma_f32_16x16x32_bf16(af[mi], bfr[ni], acc[mi][ni], 0, 0, 0);
  }
  float bcol[4];
  if (BIAS) {
#pragma unroll
    for (int ni = 0; ni < 4; ++ni) bcol[ni] = bias[bn + wn * 64 + ni * 16 + r16];
  }
#pragma unroll
  for (int mi = 0; mi < 4; ++mi)
#pragma unroll
    for (int ni = 0; ni < 4; ++ni)
#pragma unroll
      for (int r = 0; r < 4; ++r) {
        int row = bm + wm * 64 + mi * 16 + quad * 4 + r;
        if (row < M) {
          float v = acc[mi][ni][r];
          if (BIAS) v += bcol[ni];
          C[(size_t)row * N + bn + wn * 64 + ni * 16 + r16] = f2bf(v);
        }
      }
  if (ATT) {
    float La[4], Ra[4];
#pragma unroll
    for (int ni = 0; ni < 4; ++ni) {
      int cn = bn + wn * 64 + ni * 16 + r16;
      La[ni] = attL[cn]; Ra[ni] = attR[cn];
    }
#pragma unroll
    for (int mi = 0; mi < 4; ++mi)
#pragma unroll
      for (int r = 0; r < 4; ++r) {
        float sl = 0.f, sr = 0.f;
#pragma unroll
        for (int ni = 0; ni < 4; ++ni) {
          sl = fmaf(acc[mi][ni][r], La[ni], sl);
          sr = fmaf(acc[mi][ni][r], Ra[ni], sr);
        }
#pragma unroll
        for (int o = 1; o < 16; o <<= 1) {
          sl += __shfl_xor(sl, o, 64);
          sr += __shfl_xor(sr, o, 64);
        }
        if (r16 == 0) {
          int rl = wm * 64 + mi * 16 + quad * 4 + r;
          pL[wn][rl] = sl; pR[wn][rl] = sr;
        }
      }
    __syncthreads();
    if (tid < 128) {
      int row = bm + tid;
      if (row < M) {
        float sl = pL[0][tid] + pL[1][tid];
        float sr = pR[0][tid] + pR[1][tid];
        if (ATT == 1) {
          al[(size_t)row * 4 + blockIdx.y] = sl;
          ar[(size_t)row * 4 + blockIdx.y] = sr;
        } else {
          atomicAdd(&al[row], sl);
          atomicAdd(&ar[row], sr);
        }
      }
    }
  }
}

// ---------------- Big-tile bf16 MFMA GEMM, fp32 output + two bias adds ----------------
__global__ __launch_bounds__(256) void gemm_big(const unsigned short* __restrict__ A,
    const unsigned short* __restrict__ B, float* __restrict__ C, int M, int N, int K,
    const float* __restrict__ b0p, const float* __restrict__ b1p) {
  __shared__ unsigned short As[128][36];
  __shared__ unsigned short Bs[128][36];
  const int tid = threadIdx.x;
  const int wave = tid >> 6;
  const int lane = tid & 63;
  const int wm = wave & 1;
  const int wn = wave >> 1;
  const int r16 = lane & 15;
  const int quad = lane >> 4;
  const int bm = blockIdx.x * 128;
  const int bn = blockIdx.y * 128;
  const int srow = tid >> 2;
  const int scol = (tid & 3) * 8;
  int ar0 = bm + srow;      if (ar0 >= M) ar0 = M - 1;
  int ar1 = bm + 64 + srow; if (ar1 >= M) ar1 = M - 1;
  const unsigned short* Ag0 = A + (size_t)ar0 * K + scol;
  const unsigned short* Ag1 = A + (size_t)ar1 * K + scol;
  const unsigned short* Bg0 = B + (size_t)(bn + srow) * K + scol;
  const unsigned short* Bg1 = B + (size_t)(bn + 64 + srow) * K + scol;
  f32x4 acc[4][4] = {};
  for (int k0 = 0; k0 < K; k0 += 32) {
    bf16x8 a0 = *(const bf16x8*)(Ag0 + k0);
    bf16x8 a1 = *(const bf16x8*)(Ag1 + k0);
    bf16x8 b0 = *(const bf16x8*)(Bg0 + k0);
    bf16x8 b1 = *(const bf16x8*)(Bg1 + k0);
    __syncthreads();
    *(bf16x8*)(&As[srow][scol]) = a0;
    *(bf16x8*)(&As[64 + srow][scol]) = a1;
    *(bf16x8*)(&Bs[srow][scol]) = b0;
    *(bf16x8*)(&Bs[64 + srow][scol]) = b1;
    __syncthreads();
    bf16x8 af[4], bfr[4];
#pragma unroll
    for (int mi = 0; mi < 4; ++mi)
      af[mi] = *(const bf16x8*)(&As[wm * 64 + mi * 16 + r16][quad * 8]);
#pragma unroll
    for (int ni = 0; ni < 4; ++ni)
      bfr[ni] = *(const bf16x8*)(&Bs[wn * 64 + ni * 16 + r16][quad * 8]);
#pragma unroll
    for (int mi = 0; mi < 4; ++mi)
#pragma unroll
      for (int ni = 0; ni < 4; ++ni)
        acc[mi][ni] = __builtin_amdgcn_mfma_f32_16x16x32_bf16(af[mi], bfr[ni], acc[mi][ni], 0, 0, 0);
  }
  float badd[4];
#pragma unroll
  for (int ni = 0; ni < 4; ++ni) {
    int cn = bn + wn * 64 + ni * 16 + r16;
    badd[ni] = b0p[cn] + b1p[cn];
  }
#pragma unroll
  for (int mi = 0; mi < 4; ++mi)
#pragma unroll
    for (int ni = 0; ni < 4; ++ni)
#pragma unroll
      for (int r = 0; r < 4; ++r) {
        int row = bm + wm * 64 + mi * 16 + quad * 4 + r;
        if (row < M)
          C[(size_t)row * N + bn + wn * 64 + ni * 16 + r16] = acc[mi][ni][r] + badd[ni];
      }
}

// ---------------- 64x64 bf16 MFMA GEMM, fp32 out (N=64 P-projections) ----------------
__global__ __launch_bounds__(256) void gemm_bf16t(const unsigned short* __restrict__ A,
    const unsigned short* __restrict__ B, float* __restrict__ C, int M, int N, int K) {
  __shared__ unsigned short As[64][40];
  __shared__ unsigned short Bs[64][40];
  const int tid = threadIdx.x;
  const int wave = tid >> 6;
  const int lane = tid & 63;
  const int wm = wave & 1;
  const int wn = wave >> 1;
  const int r16 = lane & 15;
  const int quad = lane >> 4;
  const int bm = blockIdx.x * 64;
  const int bn = blockIdx.y * 64;
  const int srow = tid >> 2;
  const int schunk = tid & 3;
  int arow = bm + srow; if (arow >= M) arow = M - 1;
  const unsigned short* Ag = A + (size_t)arow * K + schunk * 8;
  const unsigned short* Bg = B + (size_t)(bn + srow) * K + schunk * 8;
  f32x4 acc[2][2] = {};
  for (int k0 = 0; k0 < K; k0 += 32) {
    bf16x8 av = *(const bf16x8*)(Ag + k0);
    bf16x8 bv = *(const bf16x8*)(Bg + k0);
    __syncthreads();
    *(bf16x8*)(&As[srow][schunk * 8]) = av;
    *(bf16x8*)(&Bs[srow][schunk * 8]) = bv;
    __syncthreads();
    bf16x8 af0 = *(const bf16x8*)(&As[wm * 32 + r16][quad * 8]);
    bf16x8 af1 = *(const bf16x8*)(&As[wm * 32 + 16 + r16][quad * 8]);
    bf16x8 bf0 = *(const bf16x8*)(&Bs[wn * 32 + r16][quad * 8]);
    bf16x8 bf1 = *(const bf16x8*)(&Bs[wn * 32 + 16 + r16][quad * 8]);
    acc[0][0] = __builtin_amdgcn_mfma_f32_16x16x32_bf16(af0, bf0, acc[0][0], 0, 0, 0);
    acc[0][1] = __builtin_amdgcn_mfma_f32_16x16x32_bf16(af0, bf1, acc[0][1], 0, 0, 0);
    acc[1][0] = __builtin_amdgcn_mfma_f32_16x16x32_bf16(af1, bf0, acc[1][0], 0, 0, 0);
    acc[1][1] = __builtin_amdgcn_mfma_f32_16x16x32_bf16(af1, bf1, acc[1][1], 0, 0, 0);
  }
#pragma unroll
  for (int mi = 0; mi < 2; ++mi)
#pragma unroll
    for (int ni = 0; ni < 2; ++ni)
#pragma unroll
      for (int r = 0; r < 4; ++r) {
        int row = bm + wm * 32 + mi * 16 + quad * 4 + r;
        if (row < M)
          C[(size_t)row * N + bn + wn * 32 + ni * 16 + r16] = acc[mi][ni][r];
      }
}

// ---------------- fp32 tiled GEMM (tiny M1/M2 precompute) ----------------
__global__ __launch_bounds__(256) void gemm_abt(const float* __restrict__ A,
    const float* __restrict__ B, float* __restrict__ C, int M, int N, int K) {
  __shared__ float As[32][64];
  __shared__ float Bs[32][64];
  const int tid = threadIdx.x;
  const int bm = blockIdx.y * 64;
  const int bn = blockIdx.x * 64;
  const int tx = tid & 15;
  const int ty = tid >> 4;
  const int lr = tid & 63;
  const int lq = tid >> 6;
  float acc[4][4] = {};
  for (int k0 = 0; k0 < K; k0 += 32) {
#pragma unroll
    for (int s = 0; s < 2; ++s) {
      const int q = lq + s * 4;
      const int gm = bm + lr;
      float4 va = make_float4(0.f, 0.f, 0.f, 0.f);
      if (gm < M) va = *(const float4*)(A + (size_t)gm * K + k0 + q * 4);
      As[q * 4 + 0][lr] = va.x; As[q * 4 + 1][lr] = va.y;
      As[q * 4 + 2][lr] = va.z; As[q * 4 + 3][lr] = va.w;
      const int gn = bn + lr;
      float4 vb = *(const float4*)(B + (size_t)gn * K + k0 + q * 4);
      Bs[q * 4 + 0][lr] = vb.x; Bs[q * 4 + 1][lr] = vb.y;
      Bs[q * 4 + 2][lr] = vb.z; Bs[q * 4 + 3][lr] = vb.w;
    }
    __syncthreads();
#pragma unroll
    for (int kk = 0; kk < 32; ++kk) {
      float a[4], b[4];
#pragma unroll
      for (int i2 = 0; i2 < 4; ++i2) { a[i2] = As[kk][ty * 4 + i2]; b[i2] = Bs[kk][tx * 4 + i2]; }
#pragma unroll
      for (int i2 = 0; i2 < 4; ++i2)
#pragma unroll
        for (int j2 = 0; j2 < 4; ++j2)
          acc[i2][j2] = fmaf(a[i2], b[j2], acc[i2][j2]);
    }
    __syncthreads();
  }
#pragma unroll
  for (int i2 = 0; i2 < 4; ++i2) {
    const int gm = bm + ty * 4 + i2;
    if (gm >= M) continue;
#pragma unroll
    for (int j2 = 0; j2 < 4; ++j2)
      C[(size_t)gm * N + bn + tx * 4 + j2] = acc[i2][j2];
  }
}

// ---------------- Fused prep: bf16 conversions + LoRA re-layouts + concat copies ----------------
__global__ void prep_all(const float* __restrict__ x0, const float* __restrict__ W1,
    const float* __restrict__ W2, const float* __restrict__ res_W,
    const float* __restrict__ A1, const float* __restrict__ A2,
    const float* __restrict__ B1, const float* __restrict__ B2,
    unsigned short* __restrict__ x0b, unsigned short* __restrict__ Acat,
    unsigned short* __restrict__ W1b, unsigned short* __restrict__ W2b,
    unsigned short* __restrict__ RWcat,
    float* __restrict__ Amat1, float* __restrict__ Amat2,
    unsigned short* __restrict__ Bmat1b, unsigned short* __restrict__ Bmat2b, int nx0) {
  int idx = blockIdx.x * 256 + threadIdx.x;
  if (idx < nx0) { unsigned short b = f2bf(x0[idx]); x0b[idx] = b;
    Acat[(size_t)(idx >> 7) * KCAT + (idx & 127)] = b; return; } idx -= nx0;
  if (idx < D2 * EMB) { W1b[idx] = f2bf(W1[idx]); return; } idx -= D2 * EMB;
  if (idx < OUTD * D2) { W2b[idx] = f2bf(W2[idx]); return; } idx -= OUTD * D2;
  if (idx < OUTD * EMB) { RWcat[(size_t)(idx >> 7) * KCAT + (idx & 127)] = f2bf(res_W[idx]); return; } idx -= OUTD * EMB;
  if (idx < 64 * EMB) { int d = idx % EMB, rk = idx / EMB, k = rk & 7, r = rk >> 3;
    Amat1[idx] = A1[(size_t)r * EMB * RANK + (size_t)d * RANK + k]; return; } idx -= 64 * EMB;
  if (idx < 64 * D2) { int d = idx % D2, rk = idx / D2, k = rk & 7, r = rk >> 3;
    Amat2[idx] = A2[(size_t)r * D2 * RANK + (size_t)d * RANK + k]; return; } idx -= 64 * D2;
  if (idx < 64 * EMB) { int d = idx % EMB, rk = idx / EMB, k = rk & 7, r = rk >> 3;
    Bmat1b[idx] = f2bf(B1[(size_t)r * EMB * RANK + (size_t)d * RANK + k]); return; } idx -= 64 * EMB;
  if (idx < 64 * D2) { int d = idx % D2, rk = idx / D2, k = rk & 7, r = rk >> 3;
    Bmat2b[idx] = f2bf(B2[(size_t)r * D2 * RANK + (size_t)d * RANK + k]); }
}

// ---------------- Matt folds ----------------
__global__ void fold_att(const float* __restrict__ M1, const float* __restrict__ attR1,
                         const float* __restrict__ M2, const float* __restrict__ attR2,
                         float* __restrict__ Matt1, float* __restrict__ Matt2) {
  int t = threadIdx.x;
  if (blockIdx.x == 0) {
    int h = t & 3, rk = t >> 2;
    float s = 0.f;
    for (int c = 0; c < HID; ++c)
      s = fmaf(M1[(size_t)rk * D2 + h * HID + c], attR1[h * HID + c], s);
    Matt1[rk * 4 + h] = s;
  } else if (t < 64) {
    float s = 0.f;
    for (int c = 0; c < OUTD; ++c) s = fmaf(M2[(size_t)t * OUTD + c], attR2[c], s);
    Matt2[t] = s;
  }
}

// ---------------- Build GEMM-B operands for the LoRA factorization ----------------
__global__ void build_MT(const float* __restrict__ M1, const float* __restrict__ M2,
                         unsigned short* __restrict__ M1T, unsigned short* __restrict__ RWcat) {
  int idx = blockIdx.x * 256 + threadIdx.x;
  if (idx < 512 * 256) {
    int c = idx >> 8, s = idx & 255;
    int h = s >> 6, rk = s & 63;
    float v = ((c >> 7) == h) ? M1[(size_t)rk * D2 + c] : 0.f;
    M1T[idx] = f2bf(v);
  } else {
    idx -= 512 * 256;
    if (idx < 256 * 64) {
      int c = idx >> 6, rk = idx & 63;
      RWcat[(size_t)c * KCAT + 128 + rk] = f2bf(M2[(size_t)rk * OUTD + c]);
    }
  }
}

// ---------------- CSR build ----------------
__global__ void hist_kernel(const int* __restrict__ ii, int* __restrict__ deg, int E) {
  int e = blockIdx.x * blockDim.x + threadIdx.x;
  if (e < E) atomicAdd(&deg[ii[e]], 1);
}

__global__ __launch_bounds__(1024) void exscan_kernel(const int* __restrict__ deg,
                                                      int* __restrict__ rowstart, int n) {
  __shared__ int wsum[16];
  int t = threadIdx.x;
  int lane = t & 63, wid = t >> 6;
  int carry = 0;
  for (int base = 0; base < n; base += 4096) {
    int i0 = base + t * 4;
    int v0 = 0, v1 = 0, v2 = 0, v3 = 0;
    if (i0 + 3 < n) {
      int4 vv = *(const int4*)(deg + i0);
      v0 = vv.x; v1 = vv.y; v2 = vv.z; v3 = vv.w;
    } else {
      if (i0 < n) v0 = deg[i0];
      if (i0 + 1 < n) v1 = deg[i0 + 1];
      if (i0 + 2 < n) v2 = deg[i0 + 2];
      if (i0 + 3 < n) v3 = deg[i0 + 3];
    }
    int tot = v0 + v1 + v2 + v3;
    int x = tot;
#pragma unroll
    for (int o = 1; o < 64; o <<= 1) {
      int y = __shfl_up(x, o, 64);
      if (lane >= o) x += y;
    }
    if (lane == 63) wsum[wid] = x;
    __syncthreads();
    if (t == 0) {
      int s = carry;
      for (int w2 = 0; w2 < 16; ++w2) { int tmp = wsum[w2]; wsum[w2] = s; s += tmp; }
      carry = s;
    }
    __syncthreads();
    int ex0 = x - tot + wsum[wid];
    if (i0 + 3 < n) {
      int4 ov; ov.x = ex0; ov.y = ex0 + v0; ov.z = ex0 + v0 + v1; ov.w = ex0 + v0 + v1 + v2;
      *(int4*)(rowstart + i0) = ov;
    } else {
      if (i0 < n) rowstart[i0] = ex0;
      if (i0 + 1 < n) rowstart[i0 + 1] = ex0 + v0;
      if (i0 + 2 < n) rowstart[i0 + 2] = ex0 + v0 + v1;
      if (i0 + 3 < n) rowstart[i0 + 3] = ex0 + v0 + v1 + v2;
    }
    __syncthreads();
  }
  if (t == 0) rowstart[n] = carry;
}

__global__ void scatter_kernel(const int* __restrict__ ii, const int* __restrict__ rowstart,
                               int* __restrict__ cursor, int* __restrict__ slot_of, int E) {
  int e = blockIdx.x * blockDim.x + threadIdx.x;
  if (e >= E) return;
  int i = ii[e];
  int p = atomicAdd(&cursor[i], 1);
  slot_of[e] = rowstart[i] + p;
}

// ---------------- Layer-1 edge logits -> packed records at CSR slots ----------------
// rec1 (16 floats): [j, ex0, ex1, ex2 | ex3, rt, low0, low1 | low2..low5 | low6, low7, 0, 0]
__global__ void edge_alpha1(const int* __restrict__ ji, const int* __restrict__ ii,
                            const int* __restrict__ et, const int* __restrict__ slot_of,
                            const float* __restrict__ P1,
                            const float* __restrict__ al1, const float* __restrict__ ar1,
                            const float* __restrict__ relb1, const float* __restrict__ Matt1,
                            float4* __restrict__ recs1, int E) {
  int e = blockIdx.x * blockDim.x + threadIdx.x;
  if (e >= E) return;
  int j = ji[e], i = ii[e], rt = et[e];
  float4 lo0 = *(const float4*)(P1 + (size_t)j * 64 + rt * 8);
  float4 lo1 = *(const float4*)(P1 + (size_t)j * 64 + rt * 8 + 4);
  float low[RANK] = {lo0.x, lo0.y, lo0.z, lo0.w, lo1.x, lo1.y, lo1.z, lo1.w};
  float4 ali = *(const float4*)(al1 + (size_t)i * 4);
  float4 arj = *(const float4*)(ar1 + (size_t)j * 4);
  float4 rb  = *(const float4*)(relb1 + rt * 4);
  float a0 = ali.x + arj.x + rb.x;
  float a1 = ali.y + arj.y + rb.y;
  float a2 = ali.z + arj.z + rb.z;
  float a3 = ali.w + arj.w + rb.w;
#pragma unroll
  for (int k = 0; k < RANK; ++k) {
    float4 mk = *(const float4*)(Matt1 + ((rt * 8 + k) << 2));
    a0 = fmaf(low[k], mk.x, a0); a1 = fmaf(low[k], mk.y, a1);
    a2 = fmaf(low[k], mk.z, a2); a3 = fmaf(low[k], mk.w, a3);
  }
  a0 = (a0 > 0.f) ? a0 : NEG_SLOPE * a0;
  a1 = (a1 > 0.f) ? a1 : NEG_SLOPE * a1;
  a2 = (a2 > 0.f) ? a2 : NEG_SLOPE * a2;
  a3 = (a3 > 0.f) ? a3 : NEG_SLOPE * a3;
  float e0 = expf(a0), e1 = expf(a1), e2 = expf(a2), e3 = expf(a3);
  float4* rp = recs1 + (size_t)slot_of[e] * 4;
  rp[0] = make_float4(__int_as_float(j), e0, e1, e2);
  rp[1] = make_float4(e3, __int_as_float(rt), low[0], low[1]);
  rp[2] = make_float4(low[2], low[3], low[4], low[5]);
  rp[3] = make_float4(low[6], low[7], 0.f, 0.f);
}

// ---------------- Layer-1 Q/den + in-place ex normalization ----------------
// Q1[i][h*64 + rt*8+k] = rden * sum ex_h*low_k ; then recs1 ex_h *= rden[h][rt] in place.
__global__ __launch_bounds__(256) void qden1(float4* __restrict__ recs1,
    const int* __restrict__ rowstart, unsigned short* __restrict__ Q1b, int Nn) {
  __shared__ float denS[4][32];          // [wid][h*8+rt]
  const int wid = threadIdx.x >> 6, lane = threadIdx.x & 63;
  const int i = blockIdx.x * 4 + wid;
  if (i >= Nn) return;
  const int rt_mine = lane >> 3, k = lane & 7;
  const int s0 = rowstart[i], deg = rowstart[i + 1] - s0;
  const float* rf = (const float*)recs1;
  float q0 = 0.f, q1 = 0.f, q2 = 0.f, q3 = 0.f;
  float d0 = 0.f, d1 = 0.f, d2 = 0.f, d3 = 0.f;
  float4 a0 = {}, a1 = {};
  float lw = 0.f;
  if (deg > 0) {
    a0 = recs1[(size_t)s0 * 4]; a1 = recs1[(size_t)s0 * 4 + 1];
    lw = rf[(size_t)s0 * 16 + 6 + k];
  }
  for (int p = 0; p < deg; ++p) {
    float4 b0 = a0, b1 = a1; float lwn = lw;
    if (p + 1 < deg) {
      b0 = recs1[(size_t)(s0 + p + 1) * 4]; b1 = recs1[(size_t)(s0 + p + 1) * 4 + 1];
      lwn = rf[(size_t)(s0 + p + 1) * 16 + 6 + k];
    }
    int rt = __float_as_int(a1.y);
    if (rt == rt_mine) {
      q0 = fmaf(a0.y, lw, q0); q1 = fmaf(a0.z, lw, q1);
      q2 = fmaf(a0.w, lw, q2); q3 = fmaf(a1.x, lw, q3);
      d0 += a0.y; d1 += a0.z; d2 += a0.w; d3 += a1.x;
    }
    a0 = b0; a1 = b1; lw = lwn;
  }
  float r0 = (d0 > 0.f) ? 1.f / d0 : 0.f;
  float r1 = (d1 > 0.f) ? 1.f / d1 : 0.f;
  float r2 = (d2 > 0.f) ? 1.f / d2 : 0.f;
  float r3 = (d3 > 0.f) ? 1.f / d3 : 0.f;
  size_t qb = (size_t)i * 256;
  Q1b[qb + lane]       = f2bf(q0 * r0);
  Q1b[qb + 64 + lane]  = f2bf(q1 * r1);
  Q1b[qb + 128 + lane] = f2bf(q2 * r2);
  Q1b[qb + 192 + lane] = f2bf(q3 * r3);
  if (k == 0) {
    denS[wid][rt_mine]      = r0;
    denS[wid][8 + rt_mine]  = r1;
    denS[wid][16 + rt_mine] = r2;
    denS[wid][24 + rt_mine] = r3;
  }
  // in-place normalize ex fields (lane-parallel; wave owns this CSR segment)
  for (int p = lane; p < deg; p += 64) {
    float4* rp = recs1 + (size_t)(s0 + p) * 4;
    float4 v0 = rp[0]; float4 v1 = rp[1];
    int rt = __float_as_int(v1.y);
    v0.y *= denS[wid][rt];      v0.z *= denS[wid][8 + rt];
    v0.w *= denS[wid][16 + rt]; v1.x *= denS[wid][24 + rt];
    rp[0] = v0; rp[1] = v1;
  }
}

// ---------------- Layer-1 gather: wave per node, 8 ch/lane, pure w*z accumulation ----------------
__global__ __launch_bounds__(256) void node_agg1_lite(const float4* __restrict__ recs1,
    const int* __restrict__ rowstart, const unsigned short* __restrict__ z1b,
    const unsigned short* __restrict__ L1b, unsigned short* __restrict__ h1out, int Nn) {
  const int wid = threadIdx.x >> 6;
  const int lane = threadIdx.x & 63;
  const int i = blockIdx.x * 4 + wid;
  if (i >= Nn) return;
  const int s0 = rowstart[i];
  const int deg = rowstart[i + 1] - s0;
  const int c0 = lane * 8;                 // head = lane>>4
  const float* rf = (const float*)recs1;
  float acc[8] = {};
  float4 rc = {}, rn = {};
  float w3c = 0.f, w3n = 0.f;
  uint4 zc = {};
  if (deg > 0) {
    rc = recs1[(size_t)s0 * 4];
    w3c = rf[(size_t)s0 * 16 + 4];
    zc = *(const uint4*)(z1b + (size_t)__float_as_int(rc.x) * D2 + c0);
  }
  if (deg > 1) {
    rn = recs1[(size_t)(s0 + 1) * 4];
    w3n = rf[(size_t)(s0 + 1) * 16 + 4];
  }
  for (int p = 0; p < deg; ++p) {
    float4 r2 = rn; float w32 = w3n;
    uint4 zn = zc;
    if (p + 2 < deg) {
      r2 = recs1[(size_t)(s0 + p + 2) * 4];
      w32 = rf[(size_t)(s0 + p + 2) * 16 + 4];
    }
    if (p + 1 < deg)
      zn = *(const uint4*)(z1b + (size_t)__float_as_int(rn.x) * D2 + c0);
    float wlo = (lane & 16) ? rc.z : rc.y;
    float whi = (lane & 16) ? w3c : rc.w;
    float wt = (lane & 32) ? whi : wlo;
    acc[0] = fmaf(wt, bf2f((unsigned short)(zc.x & 0xffff)), acc[0]);
    acc[1] = fmaf(wt, bf2f((unsigned short)(zc.x >> 16)), acc[1]);
    acc[2] = fmaf(wt, bf2f((unsigned short)(zc.y & 0xffff)), acc[2]);
    acc[3] = fmaf(wt, bf2f((unsigned short)(zc.y >> 16)), acc[3]);
    acc[4] = fmaf(wt, bf2f((unsigned short)(zc.z & 0xffff)), acc[4]);
    acc[5] = fmaf(wt, bf2f((unsigned short)(zc.z >> 16)), acc[5]);
    acc[6] = fmaf(wt, bf2f((unsigned short)(zc.w & 0xffff)), acc[6]);
    acc[7] = fmaf(wt, bf2f((unsigned short)(zc.w >> 16)), acc[7]);
    rc = rn; w3c = w3n; rn = r2; w3n = w32; zc = zn;
  }
  uint4 lv = *(const uint4*)(L1b + (size_t)i * D2 + c0);  // lora + bias1 (pre-folded)
  unsigned lw[4] = {lv.x, lv.y, lv.z, lv.w};
  unsigned ov[4];
#pragma unroll
  for (int q = 0; q < 4; ++q) {
    float e0 = acc[2 * q]     + bf2f((unsigned short)(lw[q] & 0xffff));
    float e1 = acc[2 * q + 1] + bf2f((unsigned short)(lw[q] >> 16));
    e0 = e0 > 0.f ? e0 : expm1f(e0);
    e1 = e1 > 0.f ? e1 : expm1f(e1);
    ov[q] = (unsigned)f2bf(e0) | ((unsigned)f2bf(e1) << 16);
  }
  *(uint4*)(h1out + (size_t)i * D2 + c0) = make_uint4(ov[0], ov[1], ov[2], ov[3]);
}

// ---------------- Layer-2 edge logits -> packed records ----------------
// rec2 (12 floats): [j, rt, ex, low0 | low1..low4 | low5, low6, low7, 0]
__global__ void edge_alpha2(const int* __restrict__ ji, const int* __restrict__ ii,
                            const int* __restrict__ et, const int* __restrict__ slot_of,
                            const float* __restrict__ P2,
                            const float* __restrict__ al2, const float* __restrict__ ar2,
                            const float* __restrict__ relb2, const float* __restrict__ Matt2,
                            float4* __restrict__ recs2, int E) {
  int e = blockIdx.x * blockDim.x + threadIdx.x;
  if (e >= E) return;
  int j = ji[e], i = ii[e], rt = et[e];
  float4 lo0 = *(const float4*)(P2 + (size_t)j * 64 + rt * 8);
  float4 lo1 = *(const float4*)(P2 + (size_t)j * 64 + rt * 8 + 4);
  float low[RANK] = {lo0.x, lo0.y, lo0.z, lo0.w, lo1.x, lo1.y, lo1.z, lo1.w};
  float a = al2[i] + ar2[j] + relb2[rt];
#pragma unroll
  for (int k = 0; k < RANK; ++k) a = fmaf(low[k], Matt2[rt * RANK + k], a);
  a = (a > 0.f) ? a : NEG_SLOPE * a;
  float ex = expf(a);
  float4* rp = recs2 + (size_t)slot_of[e] * 3;
  rp[0] = make_float4(__int_as_float(j), __int_as_float(rt), ex, low[0]);
  rp[1] = make_float4(low[1], low[2], low[3], low[4]);
  rp[2] = make_float4(low[5], low[6], low[7], 0.f);
}

// ---------------- Layer-2 Q/den + in-place ex normalization; Q -> Acat cols 128..191 ----------------
__global__ __launch_bounds__(256) void qden2(float4* __restrict__ recs2,
    const int* __restrict__ rowstart, unsigned short* __restrict__ Acat, int Nn) {
  __shared__ float denS[4][NRELS];
  const int wid = threadIdx.x >> 6, lane = threadIdx.x & 63;
  const int i = blockIdx.x * 4 + wid;
  if (i >= Nn) return;
  const int rt_mine = lane >> 3, k = lane & 7;
  const int s0 = rowstart[i], deg = rowstart[i + 1] - s0;
  const float* rf = (const float*)recs2;
  float q = 0.f, d = 0.f;
  float4 a0 = {}; float lw = 0.f;
  if (deg > 0) { a0 = recs2[(size_t)s0 * 3]; lw = rf[(size_t)s0 * 12 + 3 + k]; }
  for (int p = 0; p < deg; ++p) {
    float4 b0 = a0; float lwn = lw;
    if (p + 1 < deg) {
      b0 = recs2[(size_t)(s0 + p + 1) * 3];
      lwn = rf[(size_t)(s0 + p + 1) * 12 + 3 + k];
    }
    int rt = __float_as_int(a0.y);
    if (rt == rt_mine) { q = fmaf(a0.z, lw, q); d += a0.z; }
    a0 = b0; lw = lwn;
  }
  float rd = (d > 0.f) ? 1.f / d : 0.f;
  Acat[(size_t)i * KCAT + 128 + lane] = f2bf(q * rd);
  if (k == 0) denS[wid][rt_mine] = rd;
  for (int p = lane; p < deg; p += 64) {
    float* ep = (float*)(recs2 + (size_t)(s0 + p) * 3);
    int rt = __float_as_int(ep[1]);
    ep[2] *= denS[wid][rt];
  }
}

// ---------------- Layer-2 gather (lite) + residual/lora/bias (o2) + LN -> out ----------------
__global__ __launch_bounds__(256) void node_agg2_lite(const float4* __restrict__ recs2,
    const int* __restrict__ rowstart, const unsigned short* __restrict__ z2b,
    const float* __restrict__ o2, const float* __restrict__ ln_g,
    const float* __restrict__ ln_b, float* __restrict__ y, int Nn) {
  const int wid = threadIdx.x >> 6;
  const int lane = threadIdx.x & 63;
  const int i = blockIdx.x * 4 + wid;
  if (i >= Nn) return;
  const int s0 = rowstart[i];
  const int deg = rowstart[i + 1] - s0;
  const int c0 = lane * 4;
  float acc[4] = {};
  float4 rc = {}, rn = {};
  uint2 zc = make_uint2(0u, 0u);
  if (deg > 0) {
    rc = recs2[(size_t)s0 * 3];
    zc = *(const uint2*)(z2b + (size_t)__float_as_int(rc.x) * OUTD + c0);
  }
  if (deg > 1) rn = recs2[(size_t)(s0 + 1) * 3];
  for (int p = 0; p < deg; ++p) {
    float4 r2 = rn;
    uint2 zn = zc;
    if (p + 2 < deg) r2 = recs2[(size_t)(s0 + p + 2) * 3];
    if (p + 1 < deg)
      zn = *(const uint2*)(z2b + (size_t)__float_as_int(rn.x) * OUTD + c0);
    float wt = rc.z;                              // pre-normalized weight
    acc[0] = fmaf(wt, bf2f((unsigned short)(zc.x & 0xffff)), acc[0]);
    acc[1] = fmaf(wt, bf2f((unsigned short)(zc.x >> 16)), acc[1]);
    acc[2] = fmaf(wt, bf2f((unsigned short)(zc.y & 0xffff)), acc[2]);
    acc[3] = fmaf(wt, bf2f((unsigned short)(zc.y >> 16)), acc[3]);
    rc = rn; rn = r2; zc = zn;
  }
  float4 rsv = *(const float4*)(o2 + (size_t)i * OUTD + c0);   // residual+lora2+bias2+res_b
  float vv[4];
  vv[0] = acc[0] + rsv.x;
  vv[1] = acc[1] + rsv.y;
  vv[2] = acc[2] + rsv.z;
  vv[3] = acc[3] + rsv.w;
  float s = vv[0] + vv[1] + vv[2] + vv[3];
  for (int o = 32; o > 0; o >>= 1) s += __shfl_xor(s, o, 64);
  float mu = s * (1.f / OUTD);
  float q = 0.f;
#pragma unroll
  for (int k = 0; k < 4; ++k) { float d = vv[k] - mu; q += d * d; }
  for (int o = 32; o > 0; o >>= 1) q += __shfl_xor(q, o, 64);
  float rstd = rsqrtf(q * (1.f / OUTD) + LN_EPS);
  float4 g = *(const float4*)(ln_g + c0);
  float4 bb = *(const float4*)(ln_b + c0);
  float4 ov;
  ov.x = (vv[0] - mu) * rstd * g.x + bb.x;
  ov.y = (vv[1] - mu) * rstd * g.y + bb.y;
  ov.z = (vv[2] - mu) * rstd * g.z + bb.z;
  ov.w = (vv[3] - mu) * rstd * g.w + bb.w;
  *(float4*)(y + (size_t)i * OUTD + c0) = ov;
}

extern "C" void kernel_launch(void* const* d_in, const int* in_sizes, int n_in,
                              void* d_out, int out_size, void* d_ws, size_t ws_size,
                              hipStream_t stream) {
  const float* x0     = (const float*)d_in[0];
  const float* A1     = (const float*)d_in[1];
  const float* B1     = (const float*)d_in[2];
  const float* W1     = (const float*)d_in[3];
  const float* attL1  = (const float*)d_in[4];
  const float* attR1  = (const float*)d_in[5];
  const float* relb1  = (const float*)d_in[6];
  const float* bias1  = (const float*)d_in[7];
  const float* A2     = (const float*)d_in[8];
  const float* B2     = (const float*)d_in[9];
  const float* W2     = (const float*)d_in[10];
  const float* attL2  = (const float*)d_in[11];
  const float* attR2  = (const float*)d_in[12];
  const float* relb2  = (const float*)d_in[13];
  const float* bias2  = (const float*)d_in[14];
  const float* res_W  = (const float*)d_in[15];
  const float* res_b  = (const float*)d_in[16];
  const float* ln_g   = (const float*)d_in[17];
  const float* ln_b   = (const float*)d_in[18];
  const int*   eidx   = (const int*)d_in[19];
  const int*   etype  = (const int*)d_in[20];
  float* out = (float*)d_out;

  const int Nn = in_sizes[0] / EMB;     // 30000
  const int E  = in_sizes[20];          // 150000
  const int* ji = eidx;
  const int* ii = eidx + E;

  // ---- workspace carve-up (float units; all offsets stay 16B-aligned) ----
  float* w = (float*)d_ws;
  size_t off = 0;
  float* o2    = w + off; off += (size_t)Nn * OUTD;   // ALSO aliased as L1b (bf16 [Nn][512])
  float* P1    = w + off; off += (size_t)Nn * 64;     // ALSO aliased (with P2) as Q1b (bf16 [Nn][256])
  float* P2    = w + off; off += (size_t)Nn * 64;
  float* M1    = w + off; off += 64 * D2;
  float* M2    = w + off; off += 64 * OUTD;
  float* Amat1 = w + off; off += 64 * EMB;
  float* Amat2 = w + off; off += 64 * D2;
  float* Matt1 = w + off; off += 64 * 4;
  float* Matt2 = w + off; off += 64;
  float* al1   = w + off; off += (size_t)Nn * 4;
  float* ar1   = w + off; off += (size_t)Nn * 4;
  float* al2   = w + off; off += (size_t)Nn;
  float* ar2   = w + off; off += (size_t)Nn;
  float4* recs1 = (float4*)(w + off); off += (size_t)E * 16;
  float4* recs2 = (float4*)(w + off); off += (size_t)E * 12;
  unsigned short* z1b    = (unsigned short*)(w + off); off += (size_t)Nn * D2 / 2;
  unsigned short* z2b    = (unsigned short*)(w + off); off += (size_t)Nn * OUTD / 2;
  unsigned short* x0b    = (unsigned short*)(w + off); off += (size_t)Nn * EMB / 2;
  unsigned short* h1b    = (unsigned short*)(w + off); off += (size_t)Nn * D2 / 2;
  unsigned short* W1b    = (unsigned short*)(w + off); off += (size_t)D2 * EMB / 2;
  unsigned short* W2b    = (unsigned short*)(w + off); off += (size_t)OUTD * D2 / 2;
  unsigned short* Bmat1b = (unsigned short*)(w + off); off += (size_t)64 * EMB / 2;
  unsigned short* Bmat2b = (unsigned short*)(w + off); off += (size_t)64 * D2 / 2;
  unsigned short* Acat   = (unsigned short*)(w + off); off += (size_t)Nn * KCAT / 2;
  unsigned short* RWcat  = (unsigned short*)(w + off); off += (size_t)OUTD * KCAT / 2;
  unsigned short* M1T    = (unsigned short*)(w + off); off += (size_t)512 * 256 / 2;
  int* ideg     = (int*)(w + off); off += (size_t)Nn;
  int* cursor   = (int*)(w + off); off += (size_t)Nn;
  int* slot_of  = (int*)(w + off); off += (size_t)E;
  int* rowstart = (int*)(w + off); off += (size_t)Nn + 1;
  (void)ws_size; (void)n_in; (void)out_size;

  // Aliases (lifetimes verified):
  //  Q1b over P1+P2: P1 dead after edge_alpha1; P2 written after L1 GEMM consumed Q1b.
  //  L1b over o2:    o2 written in layer 2 (after node_agg1_lite consumed L1b).
  unsigned short* Q1b = (unsigned short*)P1;   // [Nn][256] bf16
  unsigned short* L1b = (unsigned short*)o2;   // [Nn][512] bf16

  const int MT64 = (Nn + 63) / 64;
  const int MT128 = (Nn + 127) / 128;
  const int NB4 = (Nn + 3) / 4;

  // 0) CSR build + zero the layer-2 att accumulators (filled by z2 GEMM atomics)
  (void)hipMemsetAsync(ideg, 0, (size_t)Nn * sizeof(int), stream);
  (void)hipMemsetAsync(cursor, 0, (size_t)Nn * sizeof(int), stream);
  (void)hipMemsetAsync(al2, 0, (size_t)Nn * sizeof(float), stream);
  (void)hipMemsetAsync(ar2, 0, (size_t)Nn * sizeof(float), stream);
  hist_kernel<<<(E + 255) / 256, 256, 0, stream>>>(ii, ideg, E);
  exscan_kernel<<<1, 1024, 0, stream>>>(ideg, rowstart, Nn);
  scatter_kernel<<<(E + 255) / 256, 256, 0, stream>>>(ii, rowstart, cursor, slot_of, E);

  // 1) fused conversions + LoRA re-layouts + concat copies
  {
    int nx0 = Nn * EMB;
    int total = nx0 + D2 * EMB + OUTD * D2 + OUTD * EMB + 64 * EMB + 64 * D2 + 64 * EMB + 64 * D2;
    prep_all<<<(total + 255) / 256, 256, 0, stream>>>(x0, W1, W2, res_W, A1, A2, B1, B2,
        x0b, Acat, W1b, W2b, RWcat, Amat1, Amat2, Bmat1b, Bmat2b, nx0);
  }

  // 2) M1/M2 + Matt folds + GEMM-B operand builds
  gemm_abt<<<dim3(D2 / 64, 1), 256, 0, stream>>>(Amat1, W1, M1, 64, D2, EMB);
  gemm_abt<<<dim3(OUTD / 64, 1), 256, 0, stream>>>(Amat2, W2, M2, 64, OUTD, D2);
  fold_att<<<2, 256, 0, stream>>>(M1, attR1, M2, attR2, Matt1, Matt2);
  build_MT<<<(512 * 256 + 256 * 64 + 255) / 256, 256, 0, stream>>>(M1, M2, M1T, RWcat);

  // 3) Layer-1 node GEMMs (z1 with fused att-dots per head) + P1
  gemm_big_h<1, 0><<<dim3(MT128, D2 / 128), 256, 0, stream>>>(x0b, W1b, z1b, Nn, D2, EMB,
      nullptr, attL1, attR1, al1, ar1);
  gemm_bf16t<<<dim3(MT64, 1), 256, 0, stream>>>(x0b, Bmat1b, P1, Nn, 64, EMB);

  // 4) Layer-1 edge logits; Q/den + ex normalize; LoRA GEMM (+bias1); lite gather
  edge_alpha1<<<(E + 255) / 256, 256, 0, stream>>>(ji, ii, etype, slot_of, P1, al1, ar1,
                                                   relb1, Matt1, recs1, E);
  qden1<<<NB4, 256, 0, stream>>>(recs1, rowstart, Q1b, Nn);
  gemm_big_h<0, 1><<<dim3(MT128, D2 / 128), 256, 0, stream>>>(Q1b, M1T, L1b, Nn, D2, 256,
      bias1, nullptr, nullptr, nullptr, nullptr);
  node_agg1_lite<<<NB4, 256, 0, stream>>>(recs1, rowstart, z1b, L1b, h1b, Nn);

  // 5) Layer-2 node GEMMs (z2 with fused att-dots via atomics) + P2
  gemm_big_h<2, 0><<<dim3(MT128, OUTD / 128), 256, 0, stream>>>(h1b, W2b, z2b, Nn, OUTD, D2,
      nullptr, attL2, attR2, al2, ar2);
  gemm_bf16t<<<dim3(MT64, 1), 256, 0, stream>>>(h1b, Bmat2b, P2, Nn, 64, D2);

  // 6) Layer-2 edge logits; Q/den (fills Acat) + ex normalize; fused residual+lora+bias GEMM;
  //    lite gather + LN
  edge_alpha2<<<(E + 255) / 256, 256, 0, stream>>>(ji, ii, etype, slot_of, P2, al2, ar2,
                                                   relb2, Matt2, recs2, E);
  qden2<<<NB4, 256, 0, stream>>>(recs2, rowstart, Acat, Nn);
  gemm_big<<<dim3(MT128, OUTD / 128), 256, 0, stream>>>(Acat, RWcat, o2, Nn, OUTD, KCAT,
      bias2, res_b);
  node_agg2_lite<<<NB4, 256, 0, stream>>>(recs2, rowstart, z2b, o2, ln_g, ln_b, out, Nn);
}

// Round 3
// 401.890 us; speedup vs baseline: 1.2067x; 1.0346x over previous
//
#include <hip/hip_runtime.h>
#include <cstddef>

#define NRELS 8
#define EMB 128
#define HID 128
#define OUTD 256
#define HEADS 4
#define RANK 8
#define D2 512            // HEADS*HID, conv2 input dim
#define KCAT 192          // EMB + 64, concatenated K for residual+lora2 GEMM
#define NEG_SLOPE 0.2f
#define LN_EPS 1e-5f

typedef short bf16x8 __attribute__((ext_vector_type(8)));   // 8 bf16 in 4 VGPRs
typedef float f32x4 __attribute__((ext_vector_type(4)));

__device__ __forceinline__ unsigned short f2bf(float f) {   // RNE
  union { float f; unsigned u; } v; v.f = f;
  unsigned u = v.u;
  return (unsigned short)((u + 0x7fffu + ((u >> 16) & 1u)) >> 16);
}
__device__ __forceinline__ float bf2f(unsigned short u) {
  union { unsigned u; float f; } v; v.u = (unsigned)u << 16; return v.f;
}

// async global->LDS, 16B per lane; LDS dest = wave-uniform base + lane*16
#define GLOAD16(ldsp, gp) \
  __builtin_amdgcn_global_load_lds((const __attribute__((address_space(1))) unsigned int*)(gp), \
      (__attribute__((address_space(3))) unsigned int*)(ldsp), 16, 0, 0)

// ---------------- Unified big-tile bf16 MFMA GEMM (128x128 tile, BK=32) ----------------
// global_load_lds staging, linear LDS [128][32] with source/read chunk-XOR involution.
// ATT: 0 none; 1 fused att-dots per-head (col-block == head, direct store al[row*4+by]);
//      2 fused att-dots single-head, per-col-block partials al[by*M + row].
// BIAS: add bias[col] (+ b1p[col] if F32OUT) before store.
// F32OUT: write fp32 to Cf instead of bf16 to C.
template<int ATT, int BIAS, int F32OUT>
__global__ __launch_bounds__(256) void gemm_tile(const unsigned short* __restrict__ A,
    const unsigned short* __restrict__ B, unsigned short* __restrict__ C,
    float* __restrict__ Cf, int M, int N, int K,
    const float* __restrict__ bias, const float* __restrict__ b1p,
    const float* __restrict__ attL, const float* __restrict__ attR,
    float* __restrict__ al, float* __restrict__ ar) {
  __shared__ unsigned short As[128 * 32];
  __shared__ unsigned short Bs[128 * 32];
  __shared__ float pL[2][128];
  __shared__ float pR[2][128];
  const int tid = threadIdx.x;
  const int wave = tid >> 6;
  const int lane = tid & 63;
  const int wm = wave & 1;
  const int wn = wave >> 1;
  const int r16 = lane & 15;
  const int quad = lane >> 4;
  const int bm = blockIdx.x * 128;
  const int bn = blockIdx.y * 128;
  // staging: lane covers LDS row (wave*32 + q*16 + (lane>>2)), 16B chunk (lane&3)
  // source chunk swizzled: c ^ ((row>>1)&3) == c ^ ((lane>>3)&3)
  const int lr = lane >> 2;                                  // 0..15
  const int lc = (((lane & 3) ^ ((lane >> 3) & 3))) * 8;     // swizzled col chunk (elems)
  int arow0 = bm + wave * 32 + lr;      if (arow0 >= M) arow0 = M - 1;
  int arow1 = bm + wave * 32 + 16 + lr; if (arow1 >= M) arow1 = M - 1;
  const unsigned short* Ag0 = A + (size_t)arow0 * K + lc;
  const unsigned short* Ag1 = A + (size_t)arow1 * K + lc;
  const unsigned short* Bg0 = B + (size_t)(bn + wave * 32 + lr) * K + lc;
  const unsigned short* Bg1 = B + (size_t)(bn + wave * 32 + 16 + lr) * K + lc;
  unsigned short* lA0 = As + wave * 1024;
  unsigned short* lA1 = As + wave * 1024 + 512;
  unsigned short* lB0 = Bs + wave * 1024;
  unsigned short* lB1 = Bs + wave * 1024 + 512;
  // fragment read chunk swizzle: physical chunk = quad ^ ((r16>>1)&3)
  const int rsw = (quad ^ ((r16 >> 1) & 3)) * 8;
  f32x4 acc[4][4] = {};
  for (int k0 = 0; k0 < K; k0 += 32) {
    __syncthreads();
    GLOAD16(lA0, Ag0 + k0);
    GLOAD16(lA1, Ag1 + k0);
    GLOAD16(lB0, Bg0 + k0);
    GLOAD16(lB1, Bg1 + k0);
    __syncthreads();
    bf16x8 af[4], bfr[4];
#pragma unroll
    for (int mi = 0; mi < 4; ++mi)
      af[mi] = *(const bf16x8*)(As + (wm * 64 + mi * 16 + r16) * 32 + rsw);
#pragma unroll
    for (int ni = 0; ni < 4; ++ni)
      bfr[ni] = *(const bf16x8*)(Bs + (wn * 64 + ni * 16 + r16) * 32 + rsw);
#pragma unroll
    for (int mi = 0; mi < 4; ++mi)
#pragma unroll
      for (int ni = 0; ni < 4; ++ni)
        acc[mi][ni] = __builtin_amdgcn_mfma_f32_16x16x32_bf16(af[mi], bfr[ni], acc[mi][ni], 0, 0, 0);
  }
  float bcol[4];
  if (BIAS) {
#pragma unroll
    for (int ni = 0; ni < 4; ++ni) {
      int cn = bn + wn * 64 + ni * 16 + r16;
      bcol[ni] = bias[cn];
      if (F32OUT) bcol[ni] += b1p[cn];
    }
  }
#pragma unroll
  for (int mi = 0; mi < 4; ++mi)
#pragma unroll
    for (int ni = 0; ni < 4; ++ni)
#pragma unroll
      for (int r = 0; r < 4; ++r) {
        int row = bm + wm * 64 + mi * 16 + quad * 4 + r;
        if (row < M) {
          float v = acc[mi][ni][r];
          if (BIAS) v += bcol[ni];
          size_t idx = (size_t)row * N + bn + wn * 64 + ni * 16 + r16;
          if (F32OUT) Cf[idx] = v;
          else        C[idx] = f2bf(v);
        }
      }
  if (ATT) {
    float La[4], Ra[4];
#pragma unroll
    for (int ni = 0; ni < 4; ++ni) {
      int cn = bn + wn * 64 + ni * 16 + r16;
      La[ni] = attL[cn]; Ra[ni] = attR[cn];
    }
#pragma unroll
    for (int mi = 0; mi < 4; ++mi)
#pragma unroll
      for (int r = 0; r < 4; ++r) {
        float sl = 0.f, sr = 0.f;
#pragma unroll
        for (int ni = 0; ni < 4; ++ni) {
          sl = fmaf(acc[mi][ni][r], La[ni], sl);
          sr = fmaf(acc[mi][ni][r], Ra[ni], sr);
        }
#pragma unroll
        for (int o = 1; o < 16; o <<= 1) {
          sl += __shfl_xor(sl, o, 64);
          sr += __shfl_xor(sr, o, 64);
        }
        if (r16 == 0) {
          int rl = wm * 64 + mi * 16 + quad * 4 + r;
          pL[wn][rl] = sl; pR[wn][rl] = sr;
        }
      }
    __syncthreads();
    if (tid < 128) {
      int row = bm + tid;
      if (row < M) {
        float sl = pL[0][tid] + pL[1][tid];
        float sr = pR[0][tid] + pR[1][tid];
        if (ATT == 1) {
          al[(size_t)row * 4 + blockIdx.y] = sl;
          ar[(size_t)row * 4 + blockIdx.y] = sr;
        } else {
          al[(size_t)blockIdx.y * M + row] = sl;   // per-col-block partial
          ar[(size_t)blockIdx.y * M + row] = sr;
        }
      }
    }
  }
}

// ---------------- 64x64 bf16 MFMA GEMM, fp32 out (N=64 P-projections) ----------------
__global__ __launch_bounds__(256) void gemm_bf16t(const unsigned short* __restrict__ A,
    const unsigned short* __restrict__ B, float* __restrict__ C, int M, int N, int K) {
  __shared__ unsigned short As[64][40];
  __shared__ unsigned short Bs[64][40];
  const int tid = threadIdx.x;
  const int wave = tid >> 6;
  const int lane = tid & 63;
  const int wm = wave & 1;
  const int wn = wave >> 1;
  const int r16 = lane & 15;
  const int quad = lane >> 4;
  const int bm = blockIdx.x * 64;
  const int bn = blockIdx.y * 64;
  const int srow = tid >> 2;
  const int schunk = tid & 3;
  int arow = bm + srow; if (arow >= M) arow = M - 1;
  const unsigned short* Ag = A + (size_t)arow * K + schunk * 8;
  const unsigned short* Bg = B + (size_t)(bn + srow) * K + schunk * 8;
  f32x4 acc[2][2] = {};
  for (int k0 = 0; k0 < K; k0 += 32) {
    bf16x8 av = *(const bf16x8*)(Ag + k0);
    bf16x8 bv = *(const bf16x8*)(Bg + k0);
    __syncthreads();
    *(bf16x8*)(&As[srow][schunk * 8]) = av;
    *(bf16x8*)(&Bs[srow][schunk * 8]) = bv;
    __syncthreads();
    bf16x8 af0 = *(const bf16x8*)(&As[wm * 32 + r16][quad * 8]);
    bf16x8 af1 = *(const bf16x8*)(&As[wm * 32 + 16 + r16][quad * 8]);
    bf16x8 bf0 = *(const bf16x8*)(&Bs[wn * 32 + r16][quad * 8]);
    bf16x8 bf1 = *(const bf16x8*)(&Bs[wn * 32 + 16 + r16][quad * 8]);
    acc[0][0] = __builtin_amdgcn_mfma_f32_16x16x32_bf16(af0, bf0, acc[0][0], 0, 0, 0);
    acc[0][1] = __builtin_amdgcn_mfma_f32_16x16x32_bf16(af0, bf1, acc[0][1], 0, 0, 0);
    acc[1][0] = __builtin_amdgcn_mfma_f32_16x16x32_bf16(af1, bf0, acc[1][0], 0, 0, 0);
    acc[1][1] = __builtin_amdgcn_mfma_f32_16x16x32_bf16(af1, bf1, acc[1][1], 0, 0, 0);
  }
#pragma unroll
  for (int mi = 0; mi < 2; ++mi)
#pragma unroll
    for (int ni = 0; ni < 2; ++ni)
#pragma unroll
      for (int r = 0; r < 4; ++r) {
        int row = bm + wm * 32 + mi * 16 + quad * 4 + r;
        if (row < M)
          C[(size_t)row * N + bn + wn * 32 + ni * 16 + r16] = acc[mi][ni][r];
      }
}

// ---------------- fp32 tiled GEMM (tiny M1/M2 precompute) ----------------
__global__ __launch_bounds__(256) void gemm_abt(const float* __restrict__ A,
    const float* __restrict__ B, float* __restrict__ C, int M, int N, int K) {
  __shared__ float As[32][64];
  __shared__ float Bs[32][64];
  const int tid = threadIdx.x;
  const int bm = blockIdx.y * 64;
  const int bn = blockIdx.x * 64;
  const int tx = tid & 15;
  const int ty = tid >> 4;
  const int lr = tid & 63;
  const int lq = tid >> 6;
  float acc[4][4] = {};
  for (int k0 = 0; k0 < K; k0 += 32) {
#pragma unroll
    for (int s = 0; s < 2; ++s) {
      const int q = lq + s * 4;
      const int gm = bm + lr;
      float4 va = make_float4(0.f, 0.f, 0.f, 0.f);
      if (gm < M) va = *(const float4*)(A + (size_t)gm * K + k0 + q * 4);
      As[q * 4 + 0][lr] = va.x; As[q * 4 + 1][lr] = va.y;
      As[q * 4 + 2][lr] = va.z; As[q * 4 + 3][lr] = va.w;
      const int gn = bn + lr;
      float4 vb = *(const float4*)(B + (size_t)gn * K + k0 + q * 4);
      Bs[q * 4 + 0][lr] = vb.x; Bs[q * 4 + 1][lr] = vb.y;
      Bs[q * 4 + 2][lr] = vb.z; Bs[q * 4 + 3][lr] = vb.w;
    }
    __syncthreads();
#pragma unroll
    for (int kk = 0; kk < 32; ++kk) {
      float a[4], b[4];
#pragma unroll
      for (int i2 = 0; i2 < 4; ++i2) { a[i2] = As[kk][ty * 4 + i2]; b[i2] = Bs[kk][tx * 4 + i2]; }
#pragma unroll
      for (int i2 = 0; i2 < 4; ++i2)
#pragma unroll
        for (int j2 = 0; j2 < 4; ++j2)
          acc[i2][j2] = fmaf(a[i2], b[j2], acc[i2][j2]);
    }
    __syncthreads();
  }
#pragma unroll
  for (int i2 = 0; i2 < 4; ++i2) {
    const int gm = bm + ty * 4 + i2;
    if (gm >= M) continue;
#pragma unroll
    for (int j2 = 0; j2 < 4; ++j2)
      C[(size_t)gm * N + bn + tx * 4 + j2] = acc[i2][j2];
  }
}

// ---------------- Fused prep: bf16 conversions + LoRA re-layouts + concat copies ----------------
__global__ void prep_all(const float* __restrict__ x0, const float* __restrict__ W1,
    const float* __restrict__ W2, const float* __restrict__ res_W,
    const float* __restrict__ A1, const float* __restrict__ A2,
    const float* __restrict__ B1, const float* __restrict__ B2,
    unsigned short* __restrict__ x0b, unsigned short* __restrict__ Acat,
    unsigned short* __restrict__ W1b, unsigned short* __restrict__ W2b,
    unsigned short* __restrict__ RWcat,
    float* __restrict__ Amat1, float* __restrict__ Amat2,
    unsigned short* __restrict__ Bmat1b, unsigned short* __restrict__ Bmat2b, int nx0) {
  int idx = blockIdx.x * 256 + threadIdx.x;
  if (idx < nx0) { unsigned short b = f2bf(x0[idx]); x0b[idx] = b;
    Acat[(size_t)(idx >> 7) * KCAT + (idx & 127)] = b; return; } idx -= nx0;
  if (idx < D2 * EMB) { W1b[idx] = f2bf(W1[idx]); return; } idx -= D2 * EMB;
  if (idx < OUTD * D2) { W2b[idx] = f2bf(W2[idx]); return; } idx -= OUTD * D2;
  if (idx < OUTD * EMB) { RWcat[(size_t)(idx >> 7) * KCAT + (idx & 127)] = f2bf(res_W[idx]); return; } idx -= OUTD * EMB;
  if (idx < 64 * EMB) { int d = idx % EMB, rk = idx / EMB, k = rk & 7, r = rk >> 3;
    Amat1[idx] = A1[(size_t)r * EMB * RANK + (size_t)d * RANK + k]; return; } idx -= 64 * EMB;
  if (idx < 64 * D2) { int d = idx % D2, rk = idx / D2, k = rk & 7, r = rk >> 3;
    Amat2[idx] = A2[(size_t)r * D2 * RANK + (size_t)d * RANK + k]; return; } idx -= 64 * D2;
  if (idx < 64 * EMB) { int d = idx % EMB, rk = idx / EMB, k = rk & 7, r = rk >> 3;
    Bmat1b[idx] = f2bf(B1[(size_t)r * EMB * RANK + (size_t)d * RANK + k]); return; } idx -= 64 * EMB;
  if (idx < 64 * D2) { int d = idx % D2, rk = idx / D2, k = rk & 7, r = rk >> 3;
    Bmat2b[idx] = f2bf(B2[(size_t)r * D2 * RANK + (size_t)d * RANK + k]); }
}

// ---------------- Matt folds ----------------
__global__ void fold_att(const float* __restrict__ M1, const float* __restrict__ attR1,
                         const float* __restrict__ M2, const float* __restrict__ attR2,
                         float* __restrict__ Matt1, float* __restrict__ Matt2) {
  int t = threadIdx.x;
  if (blockIdx.x == 0) {
    int h = t & 3, rk = t >> 2;
    float s = 0.f;
    for (int c = 0; c < HID; ++c)
      s = fmaf(M1[(size_t)rk * D2 + h * HID + c], attR1[h * HID + c], s);
    Matt1[rk * 4 + h] = s;
  } else if (t < 64) {
    float s = 0.f;
    for (int c = 0; c < OUTD; ++c) s = fmaf(M2[(size_t)t * OUTD + c], attR2[c], s);
    Matt2[t] = s;
  }
}

// ---------------- Build GEMM-B operands for the LoRA factorization ----------------
__global__ void build_MT(const float* __restrict__ M1, const float* __restrict__ M2,
                         unsigned short* __restrict__ M1T, unsigned short* __restrict__ RWcat) {
  int idx = blockIdx.x * 256 + threadIdx.x;
  if (idx < 512 * 256) {
    int c = idx >> 8, s = idx & 255;
    int h = s >> 6, rk = s & 63;
    float v = ((c >> 7) == h) ? M1[(size_t)rk * D2 + c] : 0.f;
    M1T[idx] = f2bf(v);
  } else {
    idx -= 512 * 256;
    if (idx < 256 * 64) {
      int c = idx >> 6, rk = idx & 63;
      RWcat[(size_t)c * KCAT + 128 + rk] = f2bf(M2[(size_t)rk * OUTD + c]);
    }
  }
}

// ---------------- CSR build ----------------
// hist also records each edge's intra-bucket position (replaces scatter pass)
__global__ void hist_kernel(const int* __restrict__ ii, int* __restrict__ deg,
                            int* __restrict__ prepos, int E) {
  int e = blockIdx.x * blockDim.x + threadIdx.x;
  if (e < E) prepos[e] = atomicAdd(&deg[ii[e]], 1);
}

__global__ __launch_bounds__(1024) void exscan_kernel(const int* __restrict__ deg,
                                                      int* __restrict__ rowstart, int n) {
  __shared__ int wsum[16];
  int t = threadIdx.x;
  int lane = t & 63, wid = t >> 6;
  int carry = 0;
  for (int base = 0; base < n; base += 4096) {
    int i0 = base + t * 4;
    int v0 = 0, v1 = 0, v2 = 0, v3 = 0;
    if (i0 + 3 < n) {
      int4 vv = *(const int4*)(deg + i0);
      v0 = vv.x; v1 = vv.y; v2 = vv.z; v3 = vv.w;
    } else {
      if (i0 < n) v0 = deg[i0];
      if (i0 + 1 < n) v1 = deg[i0 + 1];
      if (i0 + 2 < n) v2 = deg[i0 + 2];
      if (i0 + 3 < n) v3 = deg[i0 + 3];
    }
    int tot = v0 + v1 + v2 + v3;
    int x = tot;
#pragma unroll
    for (int o = 1; o < 64; o <<= 1) {
      int y = __shfl_up(x, o, 64);
      if (lane >= o) x += y;
    }
    if (lane == 63) wsum[wid] = x;
    __syncthreads();
    if (t == 0) {
      int s = carry;
      for (int w2 = 0; w2 < 16; ++w2) { int tmp = wsum[w2]; wsum[w2] = s; s += tmp; }
      carry = s;
    }
    __syncthreads();
    int ex0 = x - tot + wsum[wid];
    if (i0 + 3 < n) {
      int4 ov; ov.x = ex0; ov.y = ex0 + v0; ov.z = ex0 + v0 + v1; ov.w = ex0 + v0 + v1 + v2;
      *(int4*)(rowstart + i0) = ov;
    } else {
      if (i0 < n) rowstart[i0] = ex0;
      if (i0 + 1 < n) rowstart[i0 + 1] = ex0 + v0;
      if (i0 + 2 < n) rowstart[i0 + 2] = ex0 + v0 + v1;
      if (i0 + 3 < n) rowstart[i0 + 3] = ex0 + v0 + v1 + v2;
    }
    __syncthreads();
  }
  if (t == 0) rowstart[n] = carry;
}

// ---------------- Layer-1 edge logits -> packed records at CSR slots ----------------
// rec1 (16 floats): [j, ex0, ex1, ex2 | ex3, rt, low0, low1 | low2..low5 | low6, low7, 0, 0]
__global__ void edge_alpha1(const int* __restrict__ ji, const int* __restrict__ ii,
                            const int* __restrict__ et, const int* __restrict__ rowstart,
                            const int* __restrict__ prepos,
                            const float* __restrict__ P1,
                            const float* __restrict__ al1, const float* __restrict__ ar1,
                            const float* __restrict__ relb1, const float* __restrict__ Matt1,
                            float4* __restrict__ recs1, int E) {
  int e = blockIdx.x * blockDim.x + threadIdx.x;
  if (e >= E) return;
  int j = ji[e], i = ii[e], rt = et[e];
  float4 lo0 = *(const float4*)(P1 + (size_t)j * 64 + rt * 8);
  float4 lo1 = *(const float4*)(P1 + (size_t)j * 64 + rt * 8 + 4);
  float low[RANK] = {lo0.x, lo0.y, lo0.z, lo0.w, lo1.x, lo1.y, lo1.z, lo1.w};
  float4 ali = *(const float4*)(al1 + (size_t)i * 4);
  float4 arj = *(const float4*)(ar1 + (size_t)j * 4);
  float4 rb  = *(const float4*)(relb1 + rt * 4);
  float a0 = ali.x + arj.x + rb.x;
  float a1 = ali.y + arj.y + rb.y;
  float a2 = ali.z + arj.z + rb.z;
  float a3 = ali.w + arj.w + rb.w;
#pragma unroll
  for (int k = 0; k < RANK; ++k) {
    float4 mk = *(const float4*)(Matt1 + ((rt * 8 + k) << 2));
    a0 = fmaf(low[k], mk.x, a0); a1 = fmaf(low[k], mk.y, a1);
    a2 = fmaf(low[k], mk.z, a2); a3 = fmaf(low[k], mk.w, a3);
  }
  a0 = (a0 > 0.f) ? a0 : NEG_SLOPE * a0;
  a1 = (a1 > 0.f) ? a1 : NEG_SLOPE * a1;
  a2 = (a2 > 0.f) ? a2 : NEG_SLOPE * a2;
  a3 = (a3 > 0.f) ? a3 : NEG_SLOPE * a3;
  float e0 = expf(a0), e1 = expf(a1), e2 = expf(a2), e3 = expf(a3);
  float4* rp = recs1 + (size_t)(rowstart[i] + prepos[e]) * 4;
  rp[0] = make_float4(__int_as_float(j), e0, e1, e2);
  rp[1] = make_float4(e3, __int_as_float(rt), low[0], low[1]);
  rp[2] = make_float4(low[2], low[3], low[4], low[5]);
  rp[3] = make_float4(low[6], low[7], 0.f, 0.f);
}

// ---------------- Layer-1 Q/den + in-place ex normalization ----------------
__global__ __launch_bounds__(256) void qden1(float4* __restrict__ recs1,
    const int* __restrict__ rowstart, unsigned short* __restrict__ Q1b, int Nn) {
  __shared__ float denS[4][32];          // [wid][h*8+rt]
  const int wid = threadIdx.x >> 6, lane = threadIdx.x & 63;
  const int i = blockIdx.x * 4 + wid;
  if (i >= Nn) return;
  const int rt_mine = lane >> 3, k = lane & 7;
  const int s0 = rowstart[i], deg = rowstart[i + 1] - s0;
  const float* rf = (const float*)recs1;
  float q0 = 0.f, q1 = 0.f, q2 = 0.f, q3 = 0.f;
  float d0 = 0.f, d1 = 0.f, d2 = 0.f, d3 = 0.f;
  float4 a0 = {}, a1 = {};
  float lw = 0.f;
  if (deg > 0) {
    a0 = recs1[(size_t)s0 * 4]; a1 = recs1[(size_t)s0 * 4 + 1];
    lw = rf[(size_t)s0 * 16 + 6 + k];
  }
  for (int p = 0; p < deg; ++p) {
    float4 b0 = a0, b1 = a1; float lwn = lw;
    if (p + 1 < deg) {
      b0 = recs1[(size_t)(s0 + p + 1) * 4]; b1 = recs1[(size_t)(s0 + p + 1) * 4 + 1];
      lwn = rf[(size_t)(s0 + p + 1) * 16 + 6 + k];
    }
    int rt = __float_as_int(a1.y);
    if (rt == rt_mine) {
      q0 = fmaf(a0.y, lw, q0); q1 = fmaf(a0.z, lw, q1);
      q2 = fmaf(a0.w, lw, q2); q3 = fmaf(a1.x, lw, q3);
      d0 += a0.y; d1 += a0.z; d2 += a0.w; d3 += a1.x;
    }
    a0 = b0; a1 = b1; lw = lwn;
  }
  float r0 = (d0 > 0.f) ? 1.f / d0 : 0.f;
  float r1 = (d1 > 0.f) ? 1.f / d1 : 0.f;
  float r2 = (d2 > 0.f) ? 1.f / d2 : 0.f;
  float r3 = (d3 > 0.f) ? 1.f / d3 : 0.f;
  size_t qb = (size_t)i * 256;
  Q1b[qb + lane]       = f2bf(q0 * r0);
  Q1b[qb + 64 + lane]  = f2bf(q1 * r1);
  Q1b[qb + 128 + lane] = f2bf(q2 * r2);
  Q1b[qb + 192 + lane] = f2bf(q3 * r3);
  if (k == 0) {
    denS[wid][rt_mine]      = r0;
    denS[wid][8 + rt_mine]  = r1;
    denS[wid][16 + rt_mine] = r2;
    denS[wid][24 + rt_mine] = r3;
  }
  for (int p = lane; p < deg; p += 64) {
    float4* rp = recs1 + (size_t)(s0 + p) * 4;
    float4 v0 = rp[0]; float4 v1 = rp[1];
    int rt = __float_as_int(v1.y);
    v0.y *= denS[wid][rt];      v0.z *= denS[wid][8 + rt];
    v0.w *= denS[wid][16 + rt]; v1.x *= denS[wid][24 + rt];
    rp[0] = v0; rp[1] = v1;
  }
}

// ---------------- Layer-1 gather: wave per node, 8 ch/lane, pure w*z accumulation ----------------
__global__ __launch_bounds__(256) void node_agg1_lite(const float4* __restrict__ recs1,
    const int* __restrict__ rowstart, const unsigned short* __restrict__ z1b,
    const unsigned short* __restrict__ L1b, unsigned short* __restrict__ h1out, int Nn) {
  const int wid = threadIdx.x >> 6;
  const int lane = threadIdx.x & 63;
  const int i = blockIdx.x * 4 + wid;
  if (i >= Nn) return;
  const int s0 = rowstart[i];
  const int deg = rowstart[i + 1] - s0;
  const int c0 = lane * 8;                 // head = lane>>4
  const float* rf = (const float*)recs1;
  float acc[8] = {};
  float4 rc = {}, rn = {};
  float w3c = 0.f, w3n = 0.f;
  uint4 zc = {};
  if (deg > 0) {
    rc = recs1[(size_t)s0 * 4];
    w3c = rf[(size_t)s0 * 16 + 4];
    zc = *(const uint4*)(z1b + (size_t)__float_as_int(rc.x) * D2 + c0);
  }
  if (deg > 1) {
    rn = recs1[(size_t)(s0 + 1) * 4];
    w3n = rf[(size_t)(s0 + 1) * 16 + 4];
  }
  for (int p = 0; p < deg; ++p) {
    float4 r2 = rn; float w32 = w3n;
    uint4 zn = zc;
    if (p + 2 < deg) {
      r2 = recs1[(size_t)(s0 + p + 2) * 4];
      w32 = rf[(size_t)(s0 + p + 2) * 16 + 4];
    }
    if (p + 1 < deg)
      zn = *(const uint4*)(z1b + (size_t)__float_as_int(rn.x) * D2 + c0);
    float wlo = (lane & 16) ? rc.z : rc.y;
    float whi = (lane & 16) ? w3c : rc.w;
    float wt = (lane & 32) ? whi : wlo;
    acc[0] = fmaf(wt, bf2f((unsigned short)(zc.x & 0xffff)), acc[0]);
    acc[1] = fmaf(wt, bf2f((unsigned short)(zc.x >> 16)), acc[1]);
    acc[2] = fmaf(wt, bf2f((unsigned short)(zc.y & 0xffff)), acc[2]);
    acc[3] = fmaf(wt, bf2f((unsigned short)(zc.y >> 16)), acc[3]);
    acc[4] = fmaf(wt, bf2f((unsigned short)(zc.z & 0xffff)), acc[4]);
    acc[5] = fmaf(wt, bf2f((unsigned short)(zc.z >> 16)), acc[5]);
    acc[6] = fmaf(wt, bf2f((unsigned short)(zc.w & 0xffff)), acc[6]);
    acc[7] = fmaf(wt, bf2f((unsigned short)(zc.w >> 16)), acc[7]);
    rc = rn; w3c = w3n; rn = r2; w3n = w32; zc = zn;
  }
  uint4 lv = *(const uint4*)(L1b + (size_t)i * D2 + c0);  // lora + bias1 (pre-folded)
  unsigned lw[4] = {lv.x, lv.y, lv.z, lv.w};
  unsigned ov[4];
#pragma unroll
  for (int q = 0; q < 4; ++q) {
    float e0 = acc[2 * q]     + bf2f((unsigned short)(lw[q] & 0xffff));
    float e1 = acc[2 * q + 1] + bf2f((unsigned short)(lw[q] >> 16));
    e0 = e0 > 0.f ? e0 : expm1f(e0);
    e1 = e1 > 0.f ? e1 : expm1f(e1);
    ov[q] = (unsigned)f2bf(e0) | ((unsigned)f2bf(e1) << 16);
  }
  *(uint4*)(h1out + (size_t)i * D2 + c0) = make_uint4(ov[0], ov[1], ov[2], ov[3]);
}

// ---------------- Layer-2 edge logits -> packed records ----------------
// rec2 (12 floats): [j, rt, ex, low0 | low1..low4 | low5, low6, low7, 0]
__global__ void edge_alpha2(const int* __restrict__ ji, const int* __restrict__ ii,
                            const int* __restrict__ et, const int* __restrict__ rowstart,
                            const int* __restrict__ prepos,
                            const float* __restrict__ P2,
                            const float* __restrict__ al2, const float* __restrict__ ar2,
                            const float* __restrict__ relb2, const float* __restrict__ Matt2,
                            float4* __restrict__ recs2, int E, int Nn) {
  int e = blockIdx.x * blockDim.x + threadIdx.x;
  if (e >= E) return;
  int j = ji[e], i = ii[e], rt = et[e];
  float4 lo0 = *(const float4*)(P2 + (size_t)j * 64 + rt * 8);
  float4 lo1 = *(const float4*)(P2 + (size_t)j * 64 + rt * 8 + 4);
  float low[RANK] = {lo0.x, lo0.y, lo0.z, lo0.w, lo1.x, lo1.y, lo1.z, lo1.w};
  float a = al2[i] + al2[(size_t)Nn + i] + ar2[j] + ar2[(size_t)Nn + j] + relb2[rt];
#pragma unroll
  for (int k = 0; k < RANK; ++k) a = fmaf(low[k], Matt2[rt * RANK + k], a);
  a = (a > 0.f) ? a : NEG_SLOPE * a;
  float ex = expf(a);
  float4* rp = recs2 + (size_t)(rowstart[i] + prepos[e]) * 3;
  rp[0] = make_float4(__int_as_float(j), __int_as_float(rt), ex, low[0]);
  rp[1] = make_float4(low[1], low[2], low[3], low[4]);
  rp[2] = make_float4(low[5], low[6], low[7], 0.f);
}

// ---------------- Layer-2 Q/den + in-place ex normalization; Q -> Acat cols 128..191 ----------------
__global__ __launch_bounds__(256) void qden2(float4* __restrict__ recs2,
    const int* __restrict__ rowstart, unsigned short* __restrict__ Acat, int Nn) {
  __shared__ float denS[4][NRELS];
  const int wid = threadIdx.x >> 6, lane = threadIdx.x & 63;
  const int i = blockIdx.x * 4 + wid;
  if (i >= Nn) return;
  const int rt_mine = lane >> 3, k = lane & 7;
  const int s0 = rowstart[i], deg = rowstart[i + 1] - s0;
  const float* rf = (const float*)recs2;
  float q = 0.f, d = 0.f;
  float4 a0 = {}; float lw = 0.f;
  if (deg > 0) { a0 = recs2[(size_t)s0 * 3]; lw = rf[(size_t)s0 * 12 + 3 + k]; }
  for (int p = 0; p < deg; ++p) {
    float4 b0 = a0; float lwn = lw;
    if (p + 1 < deg) {
      b0 = recs2[(size_t)(s0 + p + 1) * 3];
      lwn = rf[(size_t)(s0 + p + 1) * 12 + 3 + k];
    }
    int rt = __float_as_int(a0.y);
    if (rt == rt_mine) { q = fmaf(a0.z, lw, q); d += a0.z; }
    a0 = b0; lw = lwn;
  }
  float rd = (d > 0.f) ? 1.f / d : 0.f;
  Acat[(size_t)i * KCAT + 128 + lane] = f2bf(q * rd);
  if (k == 0) denS[wid][rt_mine] = rd;
  for (int p = lane; p < deg; p += 64) {
    float* ep = (float*)(recs2 + (size_t)(s0 + p) * 3);
    int rt = __float_as_int(ep[1]);
    ep[2] *= denS[wid][rt];
  }
}

// ---------------- Layer-2 gather (lite) + residual/lora/bias (o2) + LN -> out ----------------
__global__ __launch_bounds__(256) void node_agg2_lite(const float4* __restrict__ recs2,
    const int* __restrict__ rowstart, const unsigned short* __restrict__ z2b,
    const float* __restrict__ o2, const float* __restrict__ ln_g,
    const float* __restrict__ ln_b, float* __restrict__ y, int Nn) {
  const int wid = threadIdx.x >> 6;
  const int lane = threadIdx.x & 63;
  const int i = blockIdx.x * 4 + wid;
  if (i >= Nn) return;
  const int s0 = rowstart[i];
  const int deg = rowstart[i + 1] - s0;
  const int c0 = lane * 4;
  float acc[4] = {};
  float4 rc = {}, rn = {};
  uint2 zc = make_uint2(0u, 0u);
  if (deg > 0) {
    rc = recs2[(size_t)s0 * 3];
    zc = *(const uint2*)(z2b + (size_t)__float_as_int(rc.x) * OUTD + c0);
  }
  if (deg > 1) rn = recs2[(size_t)(s0 + 1) * 3];
  for (int p = 0; p < deg; ++p) {
    float4 r2 = rn;
    uint2 zn = zc;
    if (p + 2 < deg) r2 = recs2[(size_t)(s0 + p + 2) * 3];
    if (p + 1 < deg)
      zn = *(const uint2*)(z2b + (size_t)__float_as_int(rn.x) * OUTD + c0);
    float wt = rc.z;                              // pre-normalized weight
    acc[0] = fmaf(wt, bf2f((unsigned short)(zc.x & 0xffff)), acc[0]);
    acc[1] = fmaf(wt, bf2f((unsigned short)(zc.x >> 16)), acc[1]);
    acc[2] = fmaf(wt, bf2f((unsigned short)(zc.y & 0xffff)), acc[2]);
    acc[3] = fmaf(wt, bf2f((unsigned short)(zc.y >> 16)), acc[3]);
    rc = rn; rn = r2; zc = zn;
  }
  float4 rsv = *(const float4*)(o2 + (size_t)i * OUTD + c0);   // residual+lora2+bias2+res_b
  float vv[4];
  vv[0] = acc[0] + rsv.x;
  vv[1] = acc[1] + rsv.y;
  vv[2] = acc[2] + rsv.z;
  vv[3] = acc[3] + rsv.w;
  float s = vv[0] + vv[1] + vv[2] + vv[3];
  for (int o = 32; o > 0; o >>= 1) s += __shfl_xor(s, o, 64);
  float mu = s * (1.f / OUTD);
  float q = 0.f;
#pragma unroll
  for (int k = 0; k < 4; ++k) { float d = vv[k] - mu; q += d * d; }
  for (int o = 32; o > 0; o >>= 1) q += __shfl_xor(q, o, 64);
  float rstd = rsqrtf(q * (1.f / OUTD) + LN_EPS);
  float4 g = *(const float4*)(ln_g + c0);
  float4 bb = *(const float4*)(ln_b + c0);
  float4 ov;
  ov.x = (vv[0] - mu) * rstd * g.x + bb.x;
  ov.y = (vv[1] - mu) * rstd * g.y + bb.y;
  ov.z = (vv[2] - mu) * rstd * g.z + bb.z;
  ov.w = (vv[3] - mu) * rstd * g.w + bb.w;
  *(float4*)(y + (size_t)i * OUTD + c0) = ov;
}

extern "C" void kernel_launch(void* const* d_in, const int* in_sizes, int n_in,
                              void* d_out, int out_size, void* d_ws, size_t ws_size,
                              hipStream_t stream) {
  const float* x0     = (const float*)d_in[0];
  const float* A1     = (const float*)d_in[1];
  const float* B1     = (const float*)d_in[2];
  const float* W1     = (const float*)d_in[3];
  const float* attL1  = (const float*)d_in[4];
  const float* attR1  = (const float*)d_in[5];
  const float* relb1  = (const float*)d_in[6];
  const float* bias1  = (const float*)d_in[7];
  const float* A2     = (const float*)d_in[8];
  const float* B2     = (const float*)d_in[9];
  const float* W2     = (const float*)d_in[10];
  const float* attL2  = (const float*)d_in[11];
  const float* attR2  = (const float*)d_in[12];
  const float* relb2  = (const float*)d_in[13];
  const float* bias2  = (const float*)d_in[14];
  const float* res_W  = (const float*)d_in[15];
  const float* res_b  = (const float*)d_in[16];
  const float* ln_g   = (const float*)d_in[17];
  const float* ln_b   = (const float*)d_in[18];
  const int*   eidx   = (const int*)d_in[19];
  const int*   etype  = (const int*)d_in[20];
  float* out = (float*)d_out;

  const int Nn = in_sizes[0] / EMB;     // 30000
  const int E  = in_sizes[20];          // 150000
  const int* ji = eidx;
  const int* ii = eidx + E;

  // ---- workspace carve-up (float units; all offsets stay 16B-aligned) ----
  float* w = (float*)d_ws;
  size_t off = 0;
  float* o2    = w + off; off += (size_t)Nn * OUTD;   // ALSO aliased as L1b (bf16 [Nn][512])
  float* P1    = w + off; off += (size_t)Nn * 64;     // ALSO aliased (with P2) as Q1b (bf16 [Nn][256])
  float* P2    = w + off; off += (size_t)Nn * 64;
  float* M1    = w + off; off += 64 * D2;
  float* M2    = w + off; off += 64 * OUTD;
  float* Amat1 = w + off; off += 64 * EMB;
  float* Amat2 = w + off; off += 64 * D2;
  float* Matt1 = w + off; off += 64 * 4;
  float* Matt2 = w + off; off += 64;
  float* al1   = w + off; off += (size_t)Nn * 4;
  float* ar1   = w + off; off += (size_t)Nn * 4;
  float* al2   = w + off; off += (size_t)Nn * 2;      // [2][Nn] col-block partials
  float* ar2   = w + off; off += (size_t)Nn * 2;
  float4* recs1 = (float4*)(w + off); off += (size_t)E * 16;
  float4* recs2 = (float4*)(w + off); off += (size_t)E * 12;
  unsigned short* z1b    = (unsigned short*)(w + off); off += (size_t)Nn * D2 / 2;
  unsigned short* z2b    = (unsigned short*)(w + off); off += (size_t)Nn * OUTD / 2;
  unsigned short* x0b    = (unsigned short*)(w + off); off += (size_t)Nn * EMB / 2;
  unsigned short* h1b    = (unsigned short*)(w + off); off += (size_t)Nn * D2 / 2;
  unsigned short* W1b    = (unsigned short*)(w + off); off += (size_t)D2 * EMB / 2;
  unsigned short* W2b    = (unsigned short*)(w + off); off += (size_t)OUTD * D2 / 2;
  unsigned short* Bmat1b = (unsigned short*)(w + off); off += (size_t)64 * EMB / 2;
  unsigned short* Bmat2b = (unsigned short*)(w + off); off += (size_t)64 * D2 / 2;
  unsigned short* Acat   = (unsigned short*)(w + off); off += (size_t)Nn * KCAT / 2;
  unsigned short* RWcat  = (unsigned short*)(w + off); off += (size_t)OUTD * KCAT / 2;
  unsigned short* M1T    = (unsigned short*)(w + off); off += (size_t)512 * 256 / 2;
  int* ideg     = (int*)(w + off); off += (size_t)Nn;
  int* prepos   = (int*)(w + off); off += (size_t)E;
  int* rowstart = (int*)(w + off); off += (size_t)Nn + 1;
  (void)ws_size; (void)n_in; (void)out_size;

  // Aliases (lifetimes verified):
  //  Q1b over P1+P2: P1 dead after edge_alpha1; P2 written after L1 GEMM consumed Q1b.
  //  L1b over o2:    o2 written in layer 2 (after node_agg1_lite consumed L1b).
  unsigned short* Q1b = (unsigned short*)P1;   // [Nn][256] bf16
  unsigned short* L1b = (unsigned short*)o2;   // [Nn][512] bf16

  const int MT64 = (Nn + 63) / 64;
  const int MT128 = (Nn + 127) / 128;
  const int NB4 = (Nn + 3) / 4;

  // 0) CSR build (hist records intra-bucket positions; no scatter pass)
  (void)hipMemsetAsync(ideg, 0, (size_t)Nn * sizeof(int), stream);
  hist_kernel<<<(E + 255) / 256, 256, 0, stream>>>(ii, ideg, prepos, E);
  exscan_kernel<<<1, 1024, 0, stream>>>(ideg, rowstart, Nn);

  // 1) fused conversions + LoRA re-layouts + concat copies
  {
    int nx0 = Nn * EMB;
    int total = nx0 + D2 * EMB + OUTD * D2 + OUTD * EMB + 64 * EMB + 64 * D2 + 64 * EMB + 64 * D2;
    prep_all<<<(total + 255) / 256, 256, 0, stream>>>(x0, W1, W2, res_W, A1, A2, B1, B2,
        x0b, Acat, W1b, W2b, RWcat, Amat1, Amat2, Bmat1b, Bmat2b, nx0);
  }

  // 2) M1/M2 + Matt folds + GEMM-B operand builds
  gemm_abt<<<dim3(D2 / 64, 1), 256, 0, stream>>>(Amat1, W1, M1, 64, D2, EMB);
  gemm_abt<<<dim3(OUTD / 64, 1), 256, 0, stream>>>(Amat2, W2, M2, 64, OUTD, D2);
  fold_att<<<2, 256, 0, stream>>>(M1, attR1, M2, attR2, Matt1, Matt2);
  build_MT<<<(512 * 256 + 256 * 64 + 255) / 256, 256, 0, stream>>>(M1, M2, M1T, RWcat);

  // 3) Layer-1 node GEMMs (z1 with fused att-dots per head) + P1
  gemm_tile<1, 0, 0><<<dim3(MT128, D2 / 128), 256, 0, stream>>>(x0b, W1b, z1b, nullptr,
      Nn, D2, EMB, nullptr, nullptr, attL1, attR1, al1, ar1);
  gemm_bf16t<<<dim3(MT64, 1), 256, 0, stream>>>(x0b, Bmat1b, P1, Nn, 64, EMB);

  // 4) Layer-1 edge logits; Q/den + ex normalize; LoRA GEMM (+bias1); lite gather
  edge_alpha1<<<(E + 255) / 256, 256, 0, stream>>>(ji, ii, etype, rowstart, prepos, P1,
                                                   al1, ar1, relb1, Matt1, recs1, E);
  qden1<<<NB4, 256, 0, stream>>>(recs1, rowstart, Q1b, Nn);
  gemm_tile<0, 1, 0><<<dim3(MT128, D2 / 128), 256, 0, stream>>>(Q1b, M1T, L1b, nullptr,
      Nn, D2, 256, bias1, nullptr, nullptr, nullptr, nullptr, nullptr);
  node_agg1_lite<<<NB4, 256, 0, stream>>>(recs1, rowstart, z1b, L1b, h1b, Nn);

  // 5) Layer-2 node GEMMs (z2 with fused att-dot partials) + P2
  gemm_tile<2, 0, 0><<<dim3(MT128, OUTD / 128), 256, 0, stream>>>(h1b, W2b, z2b, nullptr,
      Nn, OUTD, D2, nullptr, nullptr, attL2, attR2, al2, ar2);
  gemm_bf16t<<<dim3(MT64, 1), 256, 0, stream>>>(h1b, Bmat2b, P2, Nn, 64, D2);

  // 6) Layer-2 edge logits; Q/den (fills Acat) + ex normalize; fused residual+lora+bias GEMM;
  //    lite gather + LN
  edge_alpha2<<<(E + 255) / 256, 256, 0, stream>>>(ji, ii, etype, rowstart, prepos, P2,
                                                   al2, ar2, relb2, Matt2, recs2, E, Nn);
  qden2<<<NB4, 256, 0, stream>>>(recs2, rowstart, Acat, Nn);
  gemm_tile<0, 1, 1><<<dim3(MT128, OUTD / 128), 256, 0, stream>>>(Acat, RWcat, nullptr, o2,
      Nn, OUTD, KCAT, bias2, res_b, nullptr, nullptr, nullptr, nullptr);
  node_agg2_lite<<<NB4, 256, 0, stream>>>(recs2, rowstart, z2b, o2, ln_g, ln_b, out, Nn);
}

// Round 4
// 366.393 us; speedup vs baseline: 1.3237x; 1.0969x over previous
//
#include <hip/hip_runtime.h>
#include <cstddef>

#define NRELS 8
#define EMB 128
#define HID 128
#define OUTD 256
#define HEADS 4
#define RANK 8
#define D2 512            // HEADS*HID, conv2 input dim
#define KCAT 192          // EMB + 64, concatenated K for residual+lora2 GEMM
#define NEG_SLOPE 0.2f
#define LN_EPS 1e-5f

typedef short bf16x8 __attribute__((ext_vector_type(8)));   // 8 bf16 in 4 VGPRs
typedef float f32x4 __attribute__((ext_vector_type(4)));

__device__ __forceinline__ unsigned short f2bf(float f) {   // RNE
  union { float f; unsigned u; } v; v.f = f;
  unsigned u = v.u;
  return (unsigned short)((u + 0x7fffu + ((u >> 16) & 1u)) >> 16);
}
__device__ __forceinline__ float bf2f(unsigned short u) {
  union { unsigned u; float f; } v; v.u = (unsigned)u << 16; return v.f;
}

// async global->LDS, 16B per lane; LDS dest = wave-uniform base + lane*16
#define GLOAD16(ldsp, gp) \
  __builtin_amdgcn_global_load_lds((const __attribute__((address_space(1))) unsigned int*)(gp), \
      (__attribute__((address_space(3))) unsigned int*)(ldsp), 16, 0, 0)

// ---------------- Unified big-tile bf16 MFMA GEMM (128x128 tile, BK=32) ----------------
// global_load_lds staging, linear LDS [128][32] with source/read chunk-XOR involution.
// ATT: 0 none; 1 fused att-dots per-head (col-block == head, store al[row*4+by]);
//      2 fused att-dots single-head, per-col-block partials al[by*M + row].
// BIAS: add bias[col] (+ b1p[col] if F32OUT) before store.
// F32OUT: write fp32 to Cf instead of bf16 to C.
// PB: last blockIdx.y slice computes a fused 128x64 P-tile (Cp = A @ Bp^T), sharing A staging.
// lda: A row stride (elements); aoffc: per-col-block A column offset (lora1 head slices).
template<int ATT, int BIAS, int F32OUT, int PB>
__global__ __launch_bounds__(256) void gemm_tile(const unsigned short* __restrict__ A,
    const unsigned short* __restrict__ B, unsigned short* __restrict__ C,
    float* __restrict__ Cf, const unsigned short* __restrict__ Bp,
    float* __restrict__ Cp, int M, int N, int K, int lda, int aoffc,
    const float* __restrict__ bias, const float* __restrict__ b1p,
    const float* __restrict__ attL, const float* __restrict__ attR,
    float* __restrict__ al, float* __restrict__ ar) {
  __shared__ unsigned short As[128 * 32];
  __shared__ unsigned short Bs[128 * 32];
  __shared__ float pL[2][128];
  __shared__ float pR[2][128];
  const int tid = threadIdx.x;
  const int wave = tid >> 6;
  const int lane = tid & 63;
  const int wm = wave & 1;
  const int wn = wave >> 1;
  const int r16 = lane & 15;
  const int quad = lane >> 4;
  const int bm = blockIdx.x * 128;
  const int lr = lane >> 2;                                  // 0..15
  const int lc = (((lane & 3) ^ ((lane >> 3) & 3))) * 8;     // swizzled col chunk (elems)
  const int rsw = (quad ^ ((r16 >> 1) & 3)) * 8;             // fragment read swizzle
  int arow0 = bm + wave * 32 + lr;      if (arow0 >= M) arow0 = M - 1;
  int arow1 = bm + wave * 32 + 16 + lr; if (arow1 >= M) arow1 = M - 1;
  unsigned short* lA0 = As + wave * 1024;
  unsigned short* lA1 = As + wave * 1024 + 512;

  if (PB && blockIdx.y == (int)gridDim.y - 1) {
    // ---- fused P-tile: 128 rows x 64 cols, Bp is [64][K] ----
    const unsigned short* Ag0 = A + (size_t)arow0 * lda + lc;
    const unsigned short* Ag1 = A + (size_t)arow1 * lda + lc;
    const unsigned short* Bg = Bp + (size_t)(wave * 16 + lr) * K + lc;
    unsigned short* lBp = Bs + wave * 512;
    f32x4 accp[4][2] = {};
    for (int k0 = 0; k0 < K; k0 += 32) {
      __syncthreads();
      GLOAD16(lA0, Ag0 + k0);
      GLOAD16(lA1, Ag1 + k0);
      GLOAD16(lBp, Bg + k0);
      __syncthreads();
      bf16x8 af[4], bfr[2];
#pragma unroll
      for (int mi = 0; mi < 4; ++mi)
        af[mi] = *(const bf16x8*)(As + (wm * 64 + mi * 16 + r16) * 32 + rsw);
#pragma unroll
      for (int ni = 0; ni < 2; ++ni)
        bfr[ni] = *(const bf16x8*)(Bs + (wn * 32 + ni * 16 + r16) * 32 + rsw);
#pragma unroll
      for (int mi = 0; mi < 4; ++mi)
#pragma unroll
        for (int ni = 0; ni < 2; ++ni)
          accp[mi][ni] = __builtin_amdgcn_mfma_f32_16x16x32_bf16(af[mi], bfr[ni], accp[mi][ni], 0, 0, 0);
    }
#pragma unroll
    for (int mi = 0; mi < 4; ++mi)
#pragma unroll
      for (int ni = 0; ni < 2; ++ni)
#pragma unroll
        for (int r = 0; r < 4; ++r) {
          int row = bm + wm * 64 + mi * 16 + quad * 4 + r;
          if (row < M)
            Cp[(size_t)row * 64 + wn * 32 + ni * 16 + r16] = accp[mi][ni][r];
        }
    return;
  }

  const int bn = blockIdx.y * 128;
  const unsigned short* Abase = A + (size_t)blockIdx.y * aoffc;
  const unsigned short* Ag0 = Abase + (size_t)arow0 * lda + lc;
  const unsigned short* Ag1 = Abase + (size_t)arow1 * lda + lc;
  const unsigned short* Bg0 = B + (size_t)(bn + wave * 32 + lr) * K + lc;
  const unsigned short* Bg1 = B + (size_t)(bn + wave * 32 + 16 + lr) * K + lc;
  unsigned short* lB0 = Bs + wave * 1024;
  unsigned short* lB1 = Bs + wave * 1024 + 512;
  f32x4 acc[4][4] = {};
  for (int k0 = 0; k0 < K; k0 += 32) {
    __syncthreads();
    GLOAD16(lA0, Ag0 + k0);
    GLOAD16(lA1, Ag1 + k0);
    GLOAD16(lB0, Bg0 + k0);
    GLOAD16(lB1, Bg1 + k0);
    __syncthreads();
    bf16x8 af[4], bfr[4];
#pragma unroll
    for (int mi = 0; mi < 4; ++mi)
      af[mi] = *(const bf16x8*)(As + (wm * 64 + mi * 16 + r16) * 32 + rsw);
#pragma unroll
    for (int ni = 0; ni < 4; ++ni)
      bfr[ni] = *(const bf16x8*)(Bs + (wn * 64 + ni * 16 + r16) * 32 + rsw);
#pragma unroll
    for (int mi = 0; mi < 4; ++mi)
#pragma unroll
      for (int ni = 0; ni < 4; ++ni)
        acc[mi][ni] = __builtin_amdgcn_mfma_f32_16x16x32_bf16(af[mi], bfr[ni], acc[mi][ni], 0, 0, 0);
  }
  float bcol[4];
  if (BIAS) {
#pragma unroll
    for (int ni = 0; ni < 4; ++ni) {
      int cn = bn + wn * 64 + ni * 16 + r16;
      bcol[ni] = bias[cn];
      if (F32OUT) bcol[ni] += b1p[cn];
    }
  }
#pragma unroll
  for (int mi = 0; mi < 4; ++mi)
#pragma unroll
    for (int ni = 0; ni < 4; ++ni)
#pragma unroll
      for (int r = 0; r < 4; ++r) {
        int row = bm + wm * 64 + mi * 16 + quad * 4 + r;
        if (row < M) {
          float v = acc[mi][ni][r];
          if (BIAS) v += bcol[ni];
          size_t idx = (size_t)row * N + bn + wn * 64 + ni * 16 + r16;
          if (F32OUT) Cf[idx] = v;
          else        C[idx] = f2bf(v);
        }
      }
  if (ATT) {
    float La[4], Ra[4];
#pragma unroll
    for (int ni = 0; ni < 4; ++ni) {
      int cn = bn + wn * 64 + ni * 16 + r16;
      La[ni] = attL[cn]; Ra[ni] = attR[cn];
    }
#pragma unroll
    for (int mi = 0; mi < 4; ++mi)
#pragma unroll
      for (int r = 0; r < 4; ++r) {
        float sl = 0.f, sr = 0.f;
#pragma unroll
        for (int ni = 0; ni < 4; ++ni) {
          sl = fmaf(acc[mi][ni][r], La[ni], sl);
          sr = fmaf(acc[mi][ni][r], Ra[ni], sr);
        }
#pragma unroll
        for (int o = 1; o < 16; o <<= 1) {
          sl += __shfl_xor(sl, o, 64);
          sr += __shfl_xor(sr, o, 64);
        }
        if (r16 == 0) {
          int rl = wm * 64 + mi * 16 + quad * 4 + r;
          pL[wn][rl] = sl; pR[wn][rl] = sr;
        }
      }
    __syncthreads();
    if (tid < 128) {
      int row = bm + tid;
      if (row < M) {
        float sl = pL[0][tid] + pL[1][tid];
        float sr = pR[0][tid] + pR[1][tid];
        if (ATT == 1) {
          al[(size_t)row * 4 + blockIdx.y] = sl;
          ar[(size_t)row * 4 + blockIdx.y] = sr;
        } else {
          al[(size_t)blockIdx.y * M + row] = sl;   // per-col-block partial
          ar[(size_t)blockIdx.y * M + row] = sr;
        }
      }
    }
  }
}

// ---------------- fp32 tiled GEMM, both tiny M1/M2 precomputes in one dispatch ----------------
__global__ __launch_bounds__(256) void gemm_abt2(const float* __restrict__ Amat1,
    const float* __restrict__ W1, float* __restrict__ M1o,
    const float* __restrict__ Amat2, const float* __restrict__ W2, float* __restrict__ M2o) {
  const float* A; const float* B; float* C; int N, K, bn;
  if (blockIdx.x < D2 / 64) { A = Amat1; B = W1; C = M1o; N = D2; K = EMB; bn = blockIdx.x * 64; }
  else { A = Amat2; B = W2; C = M2o; N = OUTD; K = D2; bn = (blockIdx.x - D2 / 64) * 64; }
  __shared__ float As[32][64];
  __shared__ float Bs[32][64];
  const int tid = threadIdx.x;
  const int tx = tid & 15;
  const int ty = tid >> 4;
  const int lr = tid & 63;
  const int lq = tid >> 6;
  float acc[4][4] = {};
  for (int k0 = 0; k0 < K; k0 += 32) {
#pragma unroll
    for (int s = 0; s < 2; ++s) {
      const int q = lq + s * 4;
      float4 va = *(const float4*)(A + (size_t)lr * K + k0 + q * 4);
      As[q * 4 + 0][lr] = va.x; As[q * 4 + 1][lr] = va.y;
      As[q * 4 + 2][lr] = va.z; As[q * 4 + 3][lr] = va.w;
      float4 vb = *(const float4*)(B + (size_t)(bn + lr) * K + k0 + q * 4);
      Bs[q * 4 + 0][lr] = vb.x; Bs[q * 4 + 1][lr] = vb.y;
      Bs[q * 4 + 2][lr] = vb.z; Bs[q * 4 + 3][lr] = vb.w;
    }
    __syncthreads();
#pragma unroll
    for (int kk = 0; kk < 32; ++kk) {
      float a[4], b[4];
#pragma unroll
      for (int i2 = 0; i2 < 4; ++i2) { a[i2] = As[kk][ty * 4 + i2]; b[i2] = Bs[kk][tx * 4 + i2]; }
#pragma unroll
      for (int i2 = 0; i2 < 4; ++i2)
#pragma unroll
        for (int j2 = 0; j2 < 4; ++j2)
          acc[i2][j2] = fmaf(a[i2], b[j2], acc[i2][j2]);
    }
    __syncthreads();
  }
#pragma unroll
  for (int i2 = 0; i2 < 4; ++i2)
#pragma unroll
    for (int j2 = 0; j2 < 4; ++j2)
      C[(size_t)(ty * 4 + i2) * N + bn + tx * 4 + j2] = acc[i2][j2];
}

// ---------------- Fused prep: bf16 conversions + LoRA re-layouts + concat copies ----------------
__global__ void prep_all(const float* __restrict__ x0, const float* __restrict__ W1,
    const float* __restrict__ W2, const float* __restrict__ res_W,
    const float* __restrict__ A1, const float* __restrict__ A2,
    const float* __restrict__ B1, const float* __restrict__ B2,
    unsigned short* __restrict__ x0b, unsigned short* __restrict__ Acat,
    unsigned short* __restrict__ W1b, unsigned short* __restrict__ W2b,
    unsigned short* __restrict__ RWcat,
    float* __restrict__ Amat1, float* __restrict__ Amat2,
    unsigned short* __restrict__ Bmat1b, unsigned short* __restrict__ Bmat2b, int nx0) {
  int idx = blockIdx.x * 256 + threadIdx.x;
  if (idx < nx0) { unsigned short b = f2bf(x0[idx]); x0b[idx] = b;
    Acat[(size_t)(idx >> 7) * KCAT + (idx & 127)] = b; return; } idx -= nx0;
  if (idx < D2 * EMB) { W1b[idx] = f2bf(W1[idx]); return; } idx -= D2 * EMB;
  if (idx < OUTD * D2) { W2b[idx] = f2bf(W2[idx]); return; } idx -= OUTD * D2;
  if (idx < OUTD * EMB) { RWcat[(size_t)(idx >> 7) * KCAT + (idx & 127)] = f2bf(res_W[idx]); return; } idx -= OUTD * EMB;
  if (idx < 64 * EMB) { int d = idx % EMB, rk = idx / EMB, k = rk & 7, r = rk >> 3;
    Amat1[idx] = A1[(size_t)r * EMB * RANK + (size_t)d * RANK + k]; return; } idx -= 64 * EMB;
  if (idx < 64 * D2) { int d = idx % D2, rk = idx / D2, k = rk & 7, r = rk >> 3;
    Amat2[idx] = A2[(size_t)r * D2 * RANK + (size_t)d * RANK + k]; return; } idx -= 64 * D2;
  if (idx < 64 * EMB) { int d = idx % EMB, rk = idx / EMB, k = rk & 7, r = rk >> 3;
    Bmat1b[idx] = f2bf(B1[(size_t)r * EMB * RANK + (size_t)d * RANK + k]); return; } idx -= 64 * EMB;
  if (idx < 64 * D2) { int d = idx % D2, rk = idx / D2, k = rk & 7, r = rk >> 3;
    Bmat2b[idx] = f2bf(B2[(size_t)r * D2 * RANK + (size_t)d * RANK + k]); }
}

// ---------------- Fold Matt + build M1T2 (plain transpose) + RWcat LoRA cols ----------------
__global__ void fold_build(const float* __restrict__ M1, const float* __restrict__ M2,
                           const float* __restrict__ attR1, const float* __restrict__ attR2,
                           unsigned short* __restrict__ M1T2, unsigned short* __restrict__ RWcat,
                           float* __restrict__ Matt1, float* __restrict__ Matt2) {
  int idx = blockIdx.x * 256 + threadIdx.x;
  if (idx < 512 * 64) { int c = idx >> 6, rk = idx & 63;
    M1T2[idx] = f2bf(M1[(size_t)rk * D2 + c]); return; } idx -= 512 * 64;
  if (idx < 256 * 64) { int c = idx >> 6, rk = idx & 63;
    RWcat[(size_t)c * KCAT + 128 + rk] = f2bf(M2[(size_t)rk * OUTD + c]); return; } idx -= 256 * 64;
  if (idx < 256) { int h = idx & 3, rk = idx >> 2;
    float s = 0.f;
    for (int c = 0; c < HID; ++c)
      s = fmaf(M1[(size_t)rk * D2 + h * HID + c], attR1[h * HID + c], s);
    Matt1[rk * 4 + h] = s; return; } idx -= 256;
  if (idx < 64) {
    float s = 0.f;
    for (int c = 0; c < OUTD; ++c) s = fmaf(M2[(size_t)idx * OUTD + c], attR2[c], s);
    Matt2[idx] = s; }
}

// ---------------- CSR build ----------------
__global__ void hist_kernel(const int* __restrict__ ii, int* __restrict__ deg,
                            int* __restrict__ prepos, int E) {
  int e = blockIdx.x * blockDim.x + threadIdx.x;
  if (e < E) prepos[e] = atomicAdd(&deg[ii[e]], 1);
}

__global__ __launch_bounds__(1024) void exscan_kernel(const int* __restrict__ deg,
                                                      int* __restrict__ rowstart, int n) {
  __shared__ int wsum[16];
  int t = threadIdx.x;
  int lane = t & 63, wid = t >> 6;
  int carry = 0;
  for (int base = 0; base < n; base += 4096) {
    int i0 = base + t * 4;
    int v0 = 0, v1 = 0, v2 = 0, v3 = 0;
    if (i0 + 3 < n) {
      int4 vv = *(const int4*)(deg + i0);
      v0 = vv.x; v1 = vv.y; v2 = vv.z; v3 = vv.w;
    } else {
      if (i0 < n) v0 = deg[i0];
      if (i0 + 1 < n) v1 = deg[i0 + 1];
      if (i0 + 2 < n) v2 = deg[i0 + 2];
      if (i0 + 3 < n) v3 = deg[i0 + 3];
    }
    int tot = v0 + v1 + v2 + v3;
    int x = tot;
#pragma unroll
    for (int o = 1; o < 64; o <<= 1) {
      int y = __shfl_up(x, o, 64);
      if (lane >= o) x += y;
    }
    if (lane == 63) wsum[wid] = x;
    __syncthreads();
    if (t == 0) {
      int s = carry;
      for (int w2 = 0; w2 < 16; ++w2) { int tmp = wsum[w2]; wsum[w2] = s; s += tmp; }
      carry = s;
    }
    __syncthreads();
    int ex0 = x - tot + wsum[wid];
    if (i0 + 3 < n) {
      int4 ov; ov.x = ex0; ov.y = ex0 + v0; ov.z = ex0 + v0 + v1; ov.w = ex0 + v0 + v1 + v2;
      *(int4*)(rowstart + i0) = ov;
    } else {
      if (i0 < n) rowstart[i0] = ex0;
      if (i0 + 1 < n) rowstart[i0 + 1] = ex0 + v0;
      if (i0 + 2 < n) rowstart[i0 + 2] = ex0 + v0 + v1;
      if (i0 + 3 < n) rowstart[i0 + 3] = ex0 + v0 + v1 + v2;
    }
    __syncthreads();
  }
  if (t == 0) rowstart[n] = carry;
}

// ---------------- Layer-1 edge logits -> packed records at CSR slots ----------------
// rec1 (16 floats): [j, ex0, ex1, ex2 | ex3, rt, low0, low1 | low2..low5 | low6, low7, 0, 0]
__global__ void edge_alpha1(const int* __restrict__ ji, const int* __restrict__ ii,
                            const int* __restrict__ et, const int* __restrict__ rowstart,
                            const int* __restrict__ prepos,
                            const float* __restrict__ P1,
                            const float* __restrict__ al1, const float* __restrict__ ar1,
                            const float* __restrict__ relb1, const float* __restrict__ Matt1,
                            float4* __restrict__ recs1, int E) {
  int e = blockIdx.x * blockDim.x + threadIdx.x;
  if (e >= E) return;
  int j = ji[e], i = ii[e], rt = et[e];
  float4 lo0 = *(const float4*)(P1 + (size_t)j * 64 + rt * 8);
  float4 lo1 = *(const float4*)(P1 + (size_t)j * 64 + rt * 8 + 4);
  float low[RANK] = {lo0.x, lo0.y, lo0.z, lo0.w, lo1.x, lo1.y, lo1.z, lo1.w};
  float4 ali = *(const float4*)(al1 + (size_t)i * 4);
  float4 arj = *(const float4*)(ar1 + (size_t)j * 4);
  float4 rb  = *(const float4*)(relb1 + rt * 4);
  float a0 = ali.x + arj.x + rb.x;
  float a1 = ali.y + arj.y + rb.y;
  float a2 = ali.z + arj.z + rb.z;
  float a3 = ali.w + arj.w + rb.w;
#pragma unroll
  for (int k = 0; k < RANK; ++k) {
    float4 mk = *(const float4*)(Matt1 + ((rt * 8 + k) << 2));
    a0 = fmaf(low[k], mk.x, a0); a1 = fmaf(low[k], mk.y, a1);
    a2 = fmaf(low[k], mk.z, a2); a3 = fmaf(low[k], mk.w, a3);
  }
  a0 = (a0 > 0.f) ? a0 : NEG_SLOPE * a0;
  a1 = (a1 > 0.f) ? a1 : NEG_SLOPE * a1;
  a2 = (a2 > 0.f) ? a2 : NEG_SLOPE * a2;
  a3 = (a3 > 0.f) ? a3 : NEG_SLOPE * a3;
  float e0 = expf(a0), e1 = expf(a1), e2 = expf(a2), e3 = expf(a3);
  float4* rp = recs1 + (size_t)(rowstart[i] + prepos[e]) * 4;
  rp[0] = make_float4(__int_as_float(j), e0, e1, e2);
  rp[1] = make_float4(e3, __int_as_float(rt), low[0], low[1]);
  rp[2] = make_float4(low[2], low[3], low[4], low[5]);
  rp[3] = make_float4(low[6], low[7], 0.f, 0.f);
}

// ---------------- Layer-1 Q/den + in-place ex normalization ----------------
__global__ __launch_bounds__(256) void qden1(float4* __restrict__ recs1,
    const int* __restrict__ rowstart, unsigned short* __restrict__ Q1b, int Nn) {
  __shared__ float denS[4][32];          // [wid][h*8+rt]
  const int wid = threadIdx.x >> 6, lane = threadIdx.x & 63;
  const int i = blockIdx.x * 4 + wid;
  if (i >= Nn) return;
  const int rt_mine = lane >> 3, k = lane & 7;
  const int s0 = rowstart[i], deg = rowstart[i + 1] - s0;
  const float* rf = (const float*)recs1;
  float q0 = 0.f, q1 = 0.f, q2 = 0.f, q3 = 0.f;
  float d0 = 0.f, d1 = 0.f, d2 = 0.f, d3 = 0.f;
  float4 a0 = {}, a1 = {};
  float lw = 0.f;
  if (deg > 0) {
    a0 = recs1[(size_t)s0 * 4]; a1 = recs1[(size_t)s0 * 4 + 1];
    lw = rf[(size_t)s0 * 16 + 6 + k];
  }
  for (int p = 0; p < deg; ++p) {
    float4 b0 = a0, b1 = a1; float lwn = lw;
    if (p + 1 < deg) {
      b0 = recs1[(size_t)(s0 + p + 1) * 4]; b1 = recs1[(size_t)(s0 + p + 1) * 4 + 1];
      lwn = rf[(size_t)(s0 + p + 1) * 16 + 6 + k];
    }
    int rt = __float_as_int(a1.y);
    if (rt == rt_mine) {
      q0 = fmaf(a0.y, lw, q0); q1 = fmaf(a0.z, lw, q1);
      q2 = fmaf(a0.w, lw, q2); q3 = fmaf(a1.x, lw, q3);
      d0 += a0.y; d1 += a0.z; d2 += a0.w; d3 += a1.x;
    }
    a0 = b0; a1 = b1; lw = lwn;
  }
  float r0 = (d0 > 0.f) ? 1.f / d0 : 0.f;
  float r1 = (d1 > 0.f) ? 1.f / d1 : 0.f;
  float r2 = (d2 > 0.f) ? 1.f / d2 : 0.f;
  float r3 = (d3 > 0.f) ? 1.f / d3 : 0.f;
  size_t qb = (size_t)i * 256;
  Q1b[qb + lane]       = f2bf(q0 * r0);
  Q1b[qb + 64 + lane]  = f2bf(q1 * r1);
  Q1b[qb + 128 + lane] = f2bf(q2 * r2);
  Q1b[qb + 192 + lane] = f2bf(q3 * r3);
  if (k == 0) {
    denS[wid][rt_mine]      = r0;
    denS[wid][8 + rt_mine]  = r1;
    denS[wid][16 + rt_mine] = r2;
    denS[wid][24 + rt_mine] = r3;
  }
  for (int p = lane; p < deg; p += 64) {
    float4* rp = recs1 + (size_t)(s0 + p) * 4;
    float4 v0 = rp[0]; float4 v1 = rp[1];
    int rt = __float_as_int(v1.y);
    v0.y *= denS[wid][rt];      v0.z *= denS[wid][8 + rt];
    v0.w *= denS[wid][16 + rt]; v1.x *= denS[wid][24 + rt];
    rp[0] = v0; rp[1] = v1;
  }
}

// ---------------- Layer-1 gather: wave per node, 8 ch/lane; rec depth-3, z depth-2 ----------------
__global__ __launch_bounds__(256) void node_agg1_lite(const float4* __restrict__ recs1,
    const int* __restrict__ rowstart, const unsigned short* __restrict__ z1b,
    const unsigned short* __restrict__ L1b, unsigned short* __restrict__ h1out, int Nn) {
  const int wid = threadIdx.x >> 6;
  const int lane = threadIdx.x & 63;
  const int i = blockIdx.x * 4 + wid;
  if (i >= Nn) return;
  const int s0 = rowstart[i];
  const int deg = rowstart[i + 1] - s0;
  const int c0 = lane * 8;                 // head = lane>>4
  const float* rf = (const float*)recs1;
  float acc[8] = {};
  float4 r0 = {}, r1 = {}, r2 = {};
  float w0 = 0.f, w1 = 0.f, w2 = 0.f;
  uint4 za = {}, zb = {};
  if (deg > 0) { r0 = recs1[(size_t)s0 * 4]; w0 = rf[(size_t)s0 * 16 + 4];
    za = *(const uint4*)(z1b + (size_t)__float_as_int(r0.x) * D2 + c0); }
  if (deg > 1) { r1 = recs1[(size_t)(s0 + 1) * 4]; w1 = rf[(size_t)(s0 + 1) * 16 + 4];
    zb = *(const uint4*)(z1b + (size_t)__float_as_int(r1.x) * D2 + c0); }
  if (deg > 2) { r2 = recs1[(size_t)(s0 + 2) * 4]; w2 = rf[(size_t)(s0 + 2) * 16 + 4]; }
  for (int p = 0; p < deg; ++p) {
    float4 r3 = r2; float w3 = w2; uint4 zn = zb;
    if (p + 3 < deg) { r3 = recs1[(size_t)(s0 + p + 3) * 4];
                       w3 = rf[(size_t)(s0 + p + 3) * 16 + 4]; }
    if (p + 2 < deg) zn = *(const uint4*)(z1b + (size_t)__float_as_int(r2.x) * D2 + c0);
    float wlo = (lane & 16) ? r0.z : r0.y;
    float whi = (lane & 16) ? w0 : r0.w;
    float wt = (lane & 32) ? whi : wlo;
    acc[0] = fmaf(wt, bf2f((unsigned short)(za.x & 0xffff)), acc[0]);
    acc[1] = fmaf(wt, bf2f((unsigned short)(za.x >> 16)), acc[1]);
    acc[2] = fmaf(wt, bf2f((unsigned short)(za.y & 0xffff)), acc[2]);
    acc[3] = fmaf(wt, bf2f((unsigned short)(za.y >> 16)), acc[3]);
    acc[4] = fmaf(wt, bf2f((unsigned short)(za.z & 0xffff)), acc[4]);
    acc[5] = fmaf(wt, bf2f((unsigned short)(za.z >> 16)), acc[5]);
    acc[6] = fmaf(wt, bf2f((unsigned short)(za.w & 0xffff)), acc[6]);
    acc[7] = fmaf(wt, bf2f((unsigned short)(za.w >> 16)), acc[7]);
    r0 = r1; w0 = w1; r1 = r2; w1 = w2; r2 = r3; w2 = w3; za = zb; zb = zn;
  }
  uint4 lv = *(const uint4*)(L1b + (size_t)i * D2 + c0);  // lora + bias1 (pre-folded)
  unsigned lw[4] = {lv.x, lv.y, lv.z, lv.w};
  unsigned ov[4];
#pragma unroll
  for (int q = 0; q < 4; ++q) {
    float e0 = acc[2 * q]     + bf2f((unsigned short)(lw[q] & 0xffff));
    float e1 = acc[2 * q + 1] + bf2f((unsigned short)(lw[q] >> 16));
    e0 = e0 > 0.f ? e0 : expm1f(e0);
    e1 = e1 > 0.f ? e1 : expm1f(e1);
    ov[q] = (unsigned)f2bf(e0) | ((unsigned)f2bf(e1) << 16);
  }
  *(uint4*)(h1out + (size_t)i * D2 + c0) = make_uint4(ov[0], ov[1], ov[2], ov[3]);
}

// ---------------- Layer-2 edge logits -> packed records ----------------
// rec2 (12 floats): [j, rt, ex, low0 | low1..low4 | low5, low6, low7, 0]
__global__ void edge_alpha2(const int* __restrict__ ji, const int* __restrict__ ii,
                            const int* __restrict__ et, const int* __restrict__ rowstart,
                            const int* __restrict__ prepos,
                            const float* __restrict__ P2,
                            const float* __restrict__ al2, const float* __restrict__ ar2,
                            const float* __restrict__ relb2, const float* __restrict__ Matt2,
                            float4* __restrict__ recs2, int E, int Nn) {
  int e = blockIdx.x * blockDim.x + threadIdx.x;
  if (e >= E) return;
  int j = ji[e], i = ii[e], rt = et[e];
  float4 lo0 = *(const float4*)(P2 + (size_t)j * 64 + rt * 8);
  float4 lo1 = *(const float4*)(P2 + (size_t)j * 64 + rt * 8 + 4);
  float low[RANK] = {lo0.x, lo0.y, lo0.z, lo0.w, lo1.x, lo1.y, lo1.z, lo1.w};
  float a = al2[i] + al2[(size_t)Nn + i] + ar2[j] + ar2[(size_t)Nn + j] + relb2[rt];
#pragma unroll
  for (int k = 0; k < RANK; ++k) a = fmaf(low[k], Matt2[rt * RANK + k], a);
  a = (a > 0.f) ? a : NEG_SLOPE * a;
  float ex = expf(a);
  float4* rp = recs2 + (size_t)(rowstart[i] + prepos[e]) * 3;
  rp[0] = make_float4(__int_as_float(j), __int_as_float(rt), ex, low[0]);
  rp[1] = make_float4(low[1], low[2], low[3], low[4]);
  rp[2] = make_float4(low[5], low[6], low[7], 0.f);
}

// ---------------- Layer-2 Q/den + in-place ex normalization; Q -> Acat cols 128..191 ----------------
__global__ __launch_bounds__(256) void qden2(float4* __restrict__ recs2,
    const int* __restrict__ rowstart, unsigned short* __restrict__ Acat, int Nn) {
  __shared__ float denS[4][NRELS];
  const int wid = threadIdx.x >> 6, lane = threadIdx.x & 63;
  const int i = blockIdx.x * 4 + wid;
  if (i >= Nn) return;
  const int rt_mine = lane >> 3, k = lane & 7;
  const int s0 = rowstart[i], deg = rowstart[i + 1] - s0;
  const float* rf = (const float*)recs2;
  float q = 0.f, d = 0.f;
  float4 a0 = {}; float lw = 0.f;
  if (deg > 0) { a0 = recs2[(size_t)s0 * 3]; lw = rf[(size_t)s0 * 12 + 3 + k]; }
  for (int p = 0; p < deg; ++p) {
    float4 b0 = a0; float lwn = lw;
    if (p + 1 < deg) {
      b0 = recs2[(size_t)(s0 + p + 1) * 3];
      lwn = rf[(size_t)(s0 + p + 1) * 12 + 3 + k];
    }
    int rt = __float_as_int(a0.y);
    if (rt == rt_mine) { q = fmaf(a0.z, lw, q); d += a0.z; }
    a0 = b0; lw = lwn;
  }
  float rd = (d > 0.f) ? 1.f / d : 0.f;
  Acat[(size_t)i * KCAT + 128 + lane] = f2bf(q * rd);
  if (k == 0) denS[wid][rt_mine] = rd;
  for (int p = lane; p < deg; p += 64) {
    float* ep = (float*)(recs2 + (size_t)(s0 + p) * 3);
    int rt = __float_as_int(ep[1]);
    ep[2] *= denS[wid][rt];
  }
}

// ---------------- Layer-2 gather + residual/lora/bias (o2) + LN -> out ----------------
__global__ __launch_bounds__(256) void node_agg2_lite(const float4* __restrict__ recs2,
    const int* __restrict__ rowstart, const unsigned short* __restrict__ z2b,
    const float* __restrict__ o2, const float* __restrict__ ln_g,
    const float* __restrict__ ln_b, float* __restrict__ y, int Nn) {
  const int wid = threadIdx.x >> 6;
  const int lane = threadIdx.x & 63;
  const int i = blockIdx.x * 4 + wid;
  if (i >= Nn) return;
  const int s0 = rowstart[i];
  const int deg = rowstart[i + 1] - s0;
  const int c0 = lane * 4;
  float acc[4] = {};
  float4 r0 = {}, r1 = {}, r2 = {};
  uint2 za = make_uint2(0u, 0u), zb = make_uint2(0u, 0u);
  if (deg > 0) { r0 = recs2[(size_t)s0 * 3];
    za = *(const uint2*)(z2b + (size_t)__float_as_int(r0.x) * OUTD + c0); }
  if (deg > 1) { r1 = recs2[(size_t)(s0 + 1) * 3];
    zb = *(const uint2*)(z2b + (size_t)__float_as_int(r1.x) * OUTD + c0); }
  if (deg > 2) r2 = recs2[(size_t)(s0 + 2) * 3];
  for (int p = 0; p < deg; ++p) {
    float4 r3 = r2;
    uint2 zn = zb;
    if (p + 3 < deg) r3 = recs2[(size_t)(s0 + p + 3) * 3];
    if (p + 2 < deg)
      zn = *(const uint2*)(z2b + (size_t)__float_as_int(r2.x) * OUTD + c0);
    float wt = r0.z;                              // pre-normalized weight
    acc[0] = fmaf(wt, bf2f((unsigned short)(za.x & 0xffff)), acc[0]);
    acc[1] = fmaf(wt, bf2f((unsigned short)(za.x >> 16)), acc[1]);
    acc[2] = fmaf(wt, bf2f((unsigned short)(za.y & 0xffff)), acc[2]);
    acc[3] = fmaf(wt, bf2f((unsigned short)(za.y >> 16)), acc[3]);
    r0 = r1; r1 = r2; r2 = r3; za = zb; zb = zn;
  }
  float4 rsv = *(const float4*)(o2 + (size_t)i * OUTD + c0);   // residual+lora2+bias2+res_b
  float vv[4];
  vv[0] = acc[0] + rsv.x;
  vv[1] = acc[1] + rsv.y;
  vv[2] = acc[2] + rsv.z;
  vv[3] = acc[3] + rsv.w;
  float s = vv[0] + vv[1] + vv[2] + vv[3];
  for (int o = 32; o > 0; o >>= 1) s += __shfl_xor(s, o, 64);
  float mu = s * (1.f / OUTD);
  float q = 0.f;
#pragma unroll
  for (int k = 0; k < 4; ++k) { float d = vv[k] - mu; q += d * d; }
  for (int o = 32; o > 0; o >>= 1) q += __shfl_xor(q, o, 64);
  float rstd = rsqrtf(q * (1.f / OUTD) + LN_EPS);
  float4 g = *(const float4*)(ln_g + c0);
  float4 bb = *(const float4*)(ln_b + c0);
  float4 ov;
  ov.x = (vv[0] - mu) * rstd * g.x + bb.x;
  ov.y = (vv[1] - mu) * rstd * g.y + bb.y;
  ov.z = (vv[2] - mu) * rstd * g.z + bb.z;
  ov.w = (vv[3] - mu) * rstd * g.w + bb.w;
  *(float4*)(y + (size_t)i * OUTD + c0) = ov;
}

extern "C" void kernel_launch(void* const* d_in, const int* in_sizes, int n_in,
                              void* d_out, int out_size, void* d_ws, size_t ws_size,
                              hipStream_t stream) {
  const float* x0     = (const float*)d_in[0];
  const float* A1     = (const float*)d_in[1];
  const float* B1     = (const float*)d_in[2];
  const float* W1     = (const float*)d_in[3];
  const float* attL1  = (const float*)d_in[4];
  const float* attR1  = (const float*)d_in[5];
  const float* relb1  = (const float*)d_in[6];
  const float* bias1  = (const float*)d_in[7];
  const float* A2     = (const float*)d_in[8];
  const float* B2     = (const float*)d_in[9];
  const float* W2     = (const float*)d_in[10];
  const float* attL2  = (const float*)d_in[11];
  const float* attR2  = (const float*)d_in[12];
  const float* relb2  = (const float*)d_in[13];
  const float* bias2  = (const float*)d_in[14];
  const float* res_W  = (const float*)d_in[15];
  const float* res_b  = (const float*)d_in[16];
  const float* ln_g   = (const float*)d_in[17];
  const float* ln_b   = (const float*)d_in[18];
  const int*   eidx   = (const int*)d_in[19];
  const int*   etype  = (const int*)d_in[20];
  float* out = (float*)d_out;

  const int Nn = in_sizes[0] / EMB;     // 30000
  const int E  = in_sizes[20];          // 150000
  const int* ji = eidx;
  const int* ii = eidx + E;

  // ---- workspace carve-up (float units; all offsets stay 16B-aligned) ----
  float* w = (float*)d_ws;
  size_t off = 0;
  float* o2    = w + off; off += (size_t)Nn * OUTD;   // ALSO aliased as L1b (bf16 [Nn][512])
  float* P1    = w + off; off += (size_t)Nn * 64;     // ALSO aliased (with P2) as Q1b (bf16 [Nn][256])
  float* P2    = w + off; off += (size_t)Nn * 64;
  float* M1    = w + off; off += 64 * D2;
  float* M2    = w + off; off += 64 * OUTD;
  float* Amat1 = w + off; off += 64 * EMB;
  float* Amat2 = w + off; off += 64 * D2;
  float* Matt1 = w + off; off += 64 * 4;
  float* Matt2 = w + off; off += 64;
  float* al1   = w + off; off += (size_t)Nn * 4;
  float* ar1   = w + off; off += (size_t)Nn * 4;
  float* al2   = w + off; off += (size_t)Nn * 2;      // [2][Nn] col-block partials
  float* ar2   = w + off; off += (size_t)Nn * 2;
  float4* recs1 = (float4*)(w + off); off += (size_t)E * 16;
  float4* recs2 = (float4*)(w + off); off += (size_t)E * 12;
  unsigned short* z1b    = (unsigned short*)(w + off); off += (size_t)Nn * D2 / 2;
  unsigned short* z2b    = (unsigned short*)(w + off); off += (size_t)Nn * OUTD / 2;
  unsigned short* x0b    = (unsigned short*)(w + off); off += (size_t)Nn * EMB / 2;
  unsigned short* h1b    = (unsigned short*)(w + off); off += (size_t)Nn * D2 / 2;
  unsigned short* W1b    = (unsigned short*)(w + off); off += (size_t)D2 * EMB / 2;
  unsigned short* W2b    = (unsigned short*)(w + off); off += (size_t)OUTD * D2 / 2;
  unsigned short* Bmat1b = (unsigned short*)(w + off); off += (size_t)64 * EMB / 2;
  unsigned short* Bmat2b = (unsigned short*)(w + off); off += (size_t)64 * D2 / 2;
  unsigned short* Acat   = (unsigned short*)(w + off); off += (size_t)Nn * KCAT / 2;
  unsigned short* RWcat  = (unsigned short*)(w + off); off += (size_t)OUTD * KCAT / 2;
  unsigned short* M1T2   = (unsigned short*)(w + off); off += (size_t)512 * 64 / 2;
  int* ideg     = (int*)(w + off); off += (size_t)Nn;
  int* prepos   = (int*)(w + off); off += (size_t)E;
  int* rowstart = (int*)(w + off); off += (size_t)Nn + 1;
  (void)ws_size; (void)n_in; (void)out_size;

  // Aliases (lifetimes verified):
  //  Q1b over P1+P2: P1 dead after edge_alpha1; P2 written (z2 P-branch) after lora1 consumed Q1b.
  //  L1b over o2:    o2 written in layer 2 (after node_agg1_lite consumed L1b).
  unsigned short* Q1b = (unsigned short*)P1;   // [Nn][256] bf16
  unsigned short* L1b = (unsigned short*)o2;   // [Nn][512] bf16

  const int MT128 = (Nn + 127) / 128;
  const int NB4 = (Nn + 3) / 4;

  // 0) CSR build (hist records intra-bucket positions)
  (void)hipMemsetAsync(ideg, 0, (size_t)Nn * sizeof(int), stream);
  hist_kernel<<<(E + 255) / 256, 256, 0, stream>>>(ii, ideg, prepos, E);
  exscan_kernel<<<1, 1024, 0, stream>>>(ideg, rowstart, Nn);

  // 1) fused conversions + LoRA re-layouts + concat copies
  {
    int nx0 = Nn * EMB;
    int total = nx0 + D2 * EMB + OUTD * D2 + OUTD * EMB + 64 * EMB + 64 * D2 + 64 * EMB + 64 * D2;
    prep_all<<<(total + 255) / 256, 256, 0, stream>>>(x0, W1, W2, res_W, A1, A2, B1, B2,
        x0b, Acat, W1b, W2b, RWcat, Amat1, Amat2, Bmat1b, Bmat2b, nx0);
  }

  // 2) M1/M2 (one dispatch) + folds/builds (one dispatch)
  gemm_abt2<<<dim3(D2 / 64 + OUTD / 64, 1), 256, 0, stream>>>(Amat1, W1, M1, Amat2, W2, M2);
  fold_build<<<(512 * 64 + 256 * 64 + 256 + 64 + 255) / 256, 256, 0, stream>>>(
      M1, M2, attR1, attR2, M1T2, RWcat, Matt1, Matt2);

  // 3) Layer-1: z1 GEMM (+fused att-dots, +fused P1 tile)
  gemm_tile<1, 0, 0, 1><<<dim3(MT128, D2 / 128 + 1), 256, 0, stream>>>(x0b, W1b, z1b, nullptr,
      Bmat1b, P1, Nn, D2, EMB, EMB, 0, nullptr, nullptr, attL1, attR1, al1, ar1);

  // 4) Layer-1 edge logits; Q/den + ex normalize; LoRA GEMM (K=64 per-head, +bias1); gather
  edge_alpha1<<<(E + 255) / 256, 256, 0, stream>>>(ji, ii, etype, rowstart, prepos, P1,
                                                   al1, ar1, relb1, Matt1, recs1, E);
  qden1<<<NB4, 256, 0, stream>>>(recs1, rowstart, Q1b, Nn);
  gemm_tile<0, 1, 0, 0><<<dim3(MT128, D2 / 128), 256, 0, stream>>>(Q1b, M1T2, L1b, nullptr,
      nullptr, nullptr, Nn, D2, 64, 256, 64, bias1, nullptr, nullptr, nullptr, nullptr, nullptr);
  node_agg1_lite<<<NB4, 256, 0, stream>>>(recs1, rowstart, z1b, L1b, h1b, Nn);

  // 5) Layer-2: z2 GEMM (+fused att-dot partials, +fused P2 tile)
  gemm_tile<2, 0, 0, 1><<<dim3(MT128, OUTD / 128 + 1), 256, 0, stream>>>(h1b, W2b, z2b, nullptr,
      Bmat2b, P2, Nn, OUTD, D2, D2, 0, nullptr, nullptr, attL2, attR2, al2, ar2);

  // 6) Layer-2 edge logits; Q/den (fills Acat); fused residual+lora+bias GEMM; gather + LN
  edge_alpha2<<<(E + 255) / 256, 256, 0, stream>>>(ji, ii, etype, rowstart, prepos, P2,
                                                   al2, ar2, relb2, Matt2, recs2, E, Nn);
  qden2<<<NB4, 256, 0, stream>>>(recs2, rowstart, Acat, Nn);
  gemm_tile<0, 1, 1, 0><<<dim3(MT128, OUTD / 128), 256, 0, stream>>>(Acat, RWcat, nullptr, o2,
      nullptr, nullptr, Nn, OUTD, KCAT, KCAT, 0, bias2, res_b, nullptr, nullptr, nullptr, nullptr);
  node_agg2_lite<<<NB4, 256, 0, stream>>>(recs2, rowstart, z2b, o2, ln_g, ln_b, out, Nn);
}